// Round 9
// baseline (508.179 us; speedup 1.0000x reference)
//
#include <hip/hip_runtime.h>
#include <math.h>

// Problem constants (B=2, S=2048, H=1024, NH=8, HD=128)
static constexpr int Bz = 2;
static constexpr int Sq = 2048;
static constexpr int Hh = 1024;
static constexpr int NH = 8;
static constexpr int HD = 128;
static constexpr int H3 = 3072;
static constexpr int H6 = 6144;

typedef unsigned short ushort_t;
typedef float f32x4v __attribute__((ext_vector_type(4)));
typedef float f32x16v __attribute__((ext_vector_type(16)));
typedef short s16x8 __attribute__((ext_vector_type(8)));

// Workspace layout in float units (×4 bytes). Peak ~146 MB.
static constexpr size_t FUSED_OFF = 0;          // bf16 [4096][6144] = 12,582,912 f
static constexpr size_t A2_OFF    = 12582912;   // bf16 [4096][3072] =  6,291,456 f
static constexpr size_t HB_OFF    = 18874368;   // bf16 [4096][1024] (dead after gemm_silu)
static constexpr size_t MBITS_OFF = 18874368;   // u8 [2][2048][256] = 1 MB (OVERLAYS hb)
static constexpr size_t WQT_OFF   = 20971520;   // bf16 [6144][1024] (dead after gemm_silu)
static constexpr size_t WOT_OFF   = 24117248;   // bf16 [1024][3072] =  1,572,864 f
static constexpr size_t QR_OFF    = 25690112;   // bf16 [4096][1024] =  2,097,152 f
static constexpr size_t KR_OFF    = 27787264;   // bf16 [4096][1024] =  2,097,152 f
static constexpr size_t VT_OFF    = 29884416;   // bf16 [16][128][2048] = 2,097,152 f
static constexpr size_t TAB_OFF   = 31981568;   // f32 S*64 float2 = 262,144 f
static constexpr size_t FLAG_OFF  = 32243712;   // 1 int (+pad)
static constexpr size_t TSB_OFF   = 32243716;   // bf16 [2][2048][2048] -> ends 36,438,020 f

__device__ __forceinline__ float silu_(float x) { return x / (1.0f + expf(-x)); }
__device__ __forceinline__ ushort_t f2bf(float x) {
  unsigned int u = __float_as_uint(x);
  u += 0x7fffu + ((u >> 16) & 1u);
  return (ushort_t)(u >> 16);
}
__device__ __forceinline__ float bf2f(ushort_t u) {
  return __uint_as_float(((unsigned int)u) << 16);
}
// packed f32x2 -> bf16x2 (RNE), D[15:0]=lo, D[31:16]=hi
__device__ __forceinline__ unsigned int cvt_pk_bf16(float lo, float hi) {
  unsigned int r;
  asm("v_cvt_pk_bf16_f32 %0, %1, %2" : "=v"(r) : "v"(lo), "v"(hi));
  return r;
}
__device__ __forceinline__ void g2l16(const ushort_t* g, ushort_t* l) {
  __builtin_amdgcn_global_load_lds(
      (const __attribute__((address_space(1))) unsigned int*)g,
      (__attribute__((address_space(3))) unsigned int*)l, 16, 0, 0);
}

// ---------------- mask dtype detect
__global__ __launch_bounds__(256) void hstu_mask_detect(const unsigned int* __restrict__ m,
                                                        int* __restrict__ flag) {
  __shared__ int s_any;
  if (threadIdx.x == 0) s_any = 0;
  __syncthreads();
  int any = 0;
  for (int i = threadIdx.x; i < 65536; i += 256)
    if (m[i] > 1u) any = 1;
  if (any) s_any = 1;
  __syncthreads();
  if (threadIdx.x == 0) *flag = s_any;
}

// ---------------- rope table
__global__ __launch_bounds__(256) void hstu_tab(float* __restrict__ tab) {
  int t = blockIdx.x * 256 + threadIdx.x;
  int i = t & 63;
  int s = t >> 6;
  float inv = powf(10000.0f, -(float)i / 64.0f);
  float sn, cs;
  sincosf((float)s * inv, &sn, &cs);
  tab[2 * t + 0] = cs;
  tab[2 * t + 1] = sn;
}

// ---------------- mask/bias precompute: tsb = bf16(mask?bias:0), mbits = bit-packed mask
__global__ __launch_bounds__(256) void hstu_msk(const int* __restrict__ mask32,
                                                const unsigned char* __restrict__ mask8,
                                                const int* __restrict__ mflag,
                                                const float* __restrict__ bias,
                                                ushort_t* __restrict__ tsb,
                                                unsigned char* __restrict__ mbits) {
  const size_t idx = (size_t)blockIdx.x * 256 + threadIdx.x;  // over B*S*S/8
  const size_t base = idx * 8;
  const int m_u8 = *mflag;
  int mk[8];
  if (m_u8) {
    uchar4 a = *(const uchar4*)&mask8[base];
    uchar4 b = *(const uchar4*)&mask8[base + 4];
    mk[0] = a.x; mk[1] = a.y; mk[2] = a.z; mk[3] = a.w;
    mk[4] = b.x; mk[5] = b.y; mk[6] = b.z; mk[7] = b.w;
  } else {
    int4 a = *(const int4*)&mask32[base];
    int4 b = *(const int4*)&mask32[base + 4];
    mk[0] = a.x; mk[1] = a.y; mk[2] = a.z; mk[3] = a.w;
    mk[4] = b.x; mk[5] = b.y; mk[6] = b.z; mk[7] = b.w;
  }
  float4 b0 = *(const float4*)&bias[base];
  float4 b1 = *(const float4*)&bias[base + 4];
  float bb[8] = {b0.x, b0.y, b0.z, b0.w, b1.x, b1.y, b1.z, b1.w};
  ushort_t ts[8];
  unsigned int byte = 0;
#pragma unroll
  for (int i = 0; i < 8; ++i) {
    ts[i] = f2bf(mk[i] ? bb[i] : 0.0f);
    byte |= (mk[i] ? 1u : 0u) << i;
  }
  *(s16x8*)&tsb[base] = *(s16x8*)ts;
  mbits[idx] = (unsigned char)byte;
}

// ---------------- f32 -> bf16 copy (hidden)
__global__ __launch_bounds__(256) void hstu_cvt(const float* __restrict__ in,
                                                ushort_t* __restrict__ out, int n4) {
  int i = blockIdx.x * 256 + threadIdx.x;
  if (i >= n4) return;
  float4 v = *(const float4*)&in[(size_t)i * 4];
  ushort4 o;
  o.x = f2bf(v.x); o.y = f2bf(v.y); o.z = f2bf(v.z); o.w = f2bf(v.w);
  *(ushort4*)&out[(size_t)i * 4] = o;
}

// ---------------- f32 [K][N] -> bf16 [N][K] transpose-convert (weights)
__global__ __launch_bounds__(256) void hstu_cvt_t(const float* __restrict__ in,
                                                  ushort_t* __restrict__ out, int K, int N) {
  __shared__ float t[32][33];
  const int n0 = blockIdx.x * 32, k0 = blockIdx.y * 32;
  const int c = threadIdx.x & 31, rr = threadIdx.x >> 5;
#pragma unroll
  for (int p = 0; p < 4; ++p)
    t[rr + p * 8][c] = in[(size_t)(k0 + rr + p * 8) * N + n0 + c];
  __syncthreads();
#pragma unroll
  for (int p = 0; p < 4; ++p)
    out[(size_t)(n0 + rr + p * 8) * K + k0 + c] = f2bf(t[c][rr + p * 8]);
}

// ---------------- rope precompute
__global__ __launch_bounds__(256) void hstu_rope(const ushort_t* __restrict__ fused,
                                                 const float2* __restrict__ tab,
                                                 ushort_t* __restrict__ qr,
                                                 ushort_t* __restrict__ kr) {
  const int idx = blockIdx.x * 256 + threadIdx.x;
  const int row = idx >> 7;
  const int cg = (idx & 127) * 8;
  const int s = row & (Sq - 1);
  const float2* trow = &tab[(size_t)s * 64 + ((cg & 127) >> 1)];
  float2 t[4];
#pragma unroll
  for (int p = 0; p < 4; ++p) t[p] = trow[p];

  s16x8 q8 = *(const s16x8*)&fused[(size_t)row * H6 + 4 * Hh + cg];
  s16x8 k8 = *(const s16x8*)&fused[(size_t)row * H6 + 5 * Hh + cg];
  ushort_t qo[8], ko[8];
#pragma unroll
  for (int p = 0; p < 4; ++p) {
    float qx = bf2f((ushort_t)q8[2 * p]), qy = bf2f((ushort_t)q8[2 * p + 1]);
    float kx = bf2f((ushort_t)k8[2 * p]), ky = bf2f((ushort_t)k8[2 * p + 1]);
    qo[2 * p] = f2bf(qx * t[p].x - qy * t[p].y);
    qo[2 * p + 1] = f2bf(qy * t[p].x + qx * t[p].y);
    ko[2 * p] = f2bf(kx * t[p].x - ky * t[p].y);
    ko[2 * p + 1] = f2bf(ky * t[p].x + kx * t[p].y);
  }
  *(s16x8*)&qr[(size_t)row * Hh + cg] = *(s16x8*)qo;
  *(s16x8*)&kr[(size_t)row * Hh + cg] = *(s16x8*)ko;
}

// ---------------- V transpose precompute
__global__ __launch_bounds__(256) void hstu_vt(const ushort_t* __restrict__ fused,
                                               ushort_t* __restrict__ vt) {
  __shared__ ushort_t t[32][36];
  const int m0 = blockIdx.x * 32, d0 = blockIdx.y * 32, bh = blockIdx.z;
  const int b = bh >> 3, h = bh & 7;
  const int r = threadIdx.x >> 3, cg = (threadIdx.x & 7) * 4;
  *(ushort4*)&t[r][cg] =
      *(const ushort4*)&fused[(size_t)(b * Sq + m0 + r) * H6 + 3 * Hh + h * HD + d0 + cg];
  __syncthreads();
  ushort4 o;
  o.x = t[cg + 0][r]; o.y = t[cg + 1][r]; o.z = t[cg + 2][r]; o.w = t[cg + 3][r];
  *(ushort4*)&vt[(size_t)(bh * HD + d0 + r) * Sq + m0 + cg] = o;
}

// ---------------- GEMM1: fused = silu(hidden_bf @ WqT^T)  bf16 out
__global__ __launch_bounds__(256) void hstu_gemm_silu(const ushort_t* __restrict__ A,
                                                      const ushort_t* __restrict__ Bt,
                                                      ushort_t* __restrict__ C) {
  constexpr int K = 1024, N = H6;
  __shared__ ushort_t As[128 * 64];
  __shared__ ushort_t Bs[128 * 64];
  const int tid = threadIdx.x, lane = tid & 63, wid = tid >> 6;
  const int lo4 = lane & 15, hi2 = lane >> 4;
  const int wr = wid >> 1, wc = wid & 1;
  const int row0 = blockIdx.y * 128, col0 = blockIdx.x * 128;
  const int srow = lane >> 3, scol = (lane & 7) * 8;
  f32x4v acc[4][4];
#pragma unroll
  for (int i = 0; i < 4; ++i)
#pragma unroll
    for (int j = 0; j < 4; ++j) acc[i][j] = {0.f, 0.f, 0.f, 0.f};

  for (int k0 = 0; k0 < K; k0 += 64) {
    __syncthreads();
#pragma unroll
    for (int i = 0; i < 4; ++i) {
      const int rb = wid * 32 + i * 8;
      g2l16(&A[(size_t)(row0 + rb + srow) * K + k0 + scol], &As[rb * 64]);
      g2l16(&Bt[(size_t)(col0 + rb + srow) * K + k0 + scol], &Bs[rb * 64]);
    }
    __syncthreads();
#pragma unroll
    for (int kc = 0; kc < 2; ++kc) {
      s16x8 af[4], bfr[4];
#pragma unroll
      for (int mi = 0; mi < 4; ++mi)
        af[mi] = *(const s16x8*)&As[(wr * 64 + mi * 16 + lo4) * 64 + kc * 32 + hi2 * 8];
#pragma unroll
      for (int nj = 0; nj < 4; ++nj)
        bfr[nj] = *(const s16x8*)&Bs[(wc * 64 + nj * 16 + lo4) * 64 + kc * 32 + hi2 * 8];
#pragma unroll
      for (int mi = 0; mi < 4; ++mi)
#pragma unroll
        for (int nj = 0; nj < 4; ++nj)
          acc[mi][nj] = __builtin_amdgcn_mfma_f32_16x16x32_bf16(af[mi], bfr[nj], acc[mi][nj], 0, 0, 0);
    }
  }
#pragma unroll
  for (int mi = 0; mi < 4; ++mi)
#pragma unroll
    for (int nj = 0; nj < 4; ++nj)
#pragma unroll
      for (int r = 0; r < 4; ++r) {
        const int row = row0 + wr * 64 + mi * 16 + hi2 * 4 + r;
        const int col = col0 + wc * 64 + nj * 16 + lo4;
        C[(size_t)row * N + col] = f2bf(silu_(acc[mi][nj][r]));
      }
}

// ---------------- GEMM2: out = A2 @ WoT^T + b_out + hidden  f32 out
__global__ __launch_bounds__(256) void hstu_gemm_out(const ushort_t* __restrict__ A,
                                                     const ushort_t* __restrict__ Bt,
                                                     const float* __restrict__ bout,
                                                     const float* __restrict__ hidden,
                                                     float* __restrict__ C) {
  constexpr int K = H3, N = Hh;
  __shared__ ushort_t As[128 * 64];
  __shared__ ushort_t Bs[64 * 64];
  const int tid = threadIdx.x, lane = tid & 63, wid = tid >> 6;
  const int lo4 = lane & 15, hi2 = lane >> 4;
  const int wr = wid >> 1, wc = wid & 1;
  const int row0 = blockIdx.y * 128, col0 = blockIdx.x * 64;
  const int srow = lane >> 3, scol = (lane & 7) * 8;
  f32x4v acc[4][2];
#pragma unroll
  for (int i = 0; i < 4; ++i)
#pragma unroll
    for (int j = 0; j < 2; ++j) acc[i][j] = {0.f, 0.f, 0.f, 0.f};

  for (int k0 = 0; k0 < K; k0 += 64) {
    __syncthreads();
#pragma unroll
    for (int i = 0; i < 4; ++i) {
      const int rb = wid * 32 + i * 8;
      g2l16(&A[(size_t)(row0 + rb + srow) * K + k0 + scol], &As[rb * 64]);
    }
#pragma unroll
    for (int i = 0; i < 2; ++i) {
      const int rb = wid * 16 + i * 8;
      g2l16(&Bt[(size_t)(col0 + rb + srow) * K + k0 + scol], &Bs[rb * 64]);
    }
    __syncthreads();
#pragma unroll
    for (int kc = 0; kc < 2; ++kc) {
      s16x8 af[4], bfr[2];
#pragma unroll
      for (int mi = 0; mi < 4; ++mi)
        af[mi] = *(const s16x8*)&As[(wr * 64 + mi * 16 + lo4) * 64 + kc * 32 + hi2 * 8];
#pragma unroll
      for (int nj = 0; nj < 2; ++nj)
        bfr[nj] = *(const s16x8*)&Bs[(wc * 32 + nj * 16 + lo4) * 64 + kc * 32 + hi2 * 8];
#pragma unroll
      for (int mi = 0; mi < 4; ++mi)
#pragma unroll
        for (int nj = 0; nj < 2; ++nj)
          acc[mi][nj] = __builtin_amdgcn_mfma_f32_16x16x32_bf16(af[mi], bfr[nj], acc[mi][nj], 0, 0, 0);
    }
  }
#pragma unroll
  for (int mi = 0; mi < 4; ++mi)
#pragma unroll
    for (int nj = 0; nj < 2; ++nj)
#pragma unroll
      for (int r = 0; r < 4; ++r) {
        const int row = row0 + wr * 64 + mi * 16 + hi2 * 4 + r;
        const int col = col0 + wc * 32 + nj * 16 + lo4;
        C[(size_t)row * N + col] = acc[mi][nj][r] + bout[col] + hidden[(size_t)row * N + col];
      }
}

// ---------------- fused attention, bf16 mfma_32x32x16, SWAPPED scores (S^T = K x Q).
// Block: (h, nblock, b), 8 waves, QBLK=64, KVBLK=64, 2 barriers/iter.
// Scores: wave=(t_w,nq,mq) computes S^T tile -> lane holds fixed q-row n=l31, 16 m's
//   -> masked/relu'd in-register via bit-packed mask (global u32/lane) and written to
//      Pl[n][m] as packed b64 (cvt_pk), no scalar LDS ops.
// PV: wave=(nh,dq) -> 32x32 x 3 types (ts A-frags direct from global tsb).
// a2 layout: [b][n][h*384 + {0:rope|128:ts|256:plain} + d], value = attn*gated.
__global__ __launch_bounds__(512, 4) void hstu_attn(const ushort_t* __restrict__ fused,
                                                    const ushort_t* __restrict__ qr,
                                                    const ushort_t* __restrict__ kr,
                                                    const ushort_t* __restrict__ vt,
                                                    const ushort_t* __restrict__ tsb,
                                                    const unsigned int* __restrict__ mbits32,
                                                    ushort_t* __restrict__ a2) {
  __shared__ __align__(16) ushort_t Ks[64][136];        // K (also Q in prologue)
  __shared__ __align__(16) ushort_t KRs[64][136];       // roped K (also roped Q)
  __shared__ __align__(16) ushort_t Vt[128][72];        // Vt[dd][m]
  __shared__ __align__(16) ushort_t Pl[2][64][72];      // 0=plain 1=rope

  const int tid = threadIdx.x;
  const int lane = tid & 63;
  const int wid = tid >> 6;   // 0..7
  const int l31 = lane & 31;
  const int khalf = lane >> 5;  // 0/1
  const int h = blockIdx.x;     // head-first -> XCD pinning
  const int n0 = blockIdx.y * 64;
  const int b = blockIdx.z;
  const float ivs = 1.0f / 2048.0f;
  constexpr int NT = Sq / 64;

  // score role: type, n-quarter(32), m-tile(32)
  const int t_w = wid >> 2;
  const int nq = (wid >> 1) & 1;
  const int mq = wid & 1;
  // PV role: n-half(32 rows), dd-quarter(32)
  const int nh = wid & 1;
  const int dq = wid >> 1;

#define STAGE_QQR()                                                              \
  {                                                                              \
    _Pragma("unroll") for (int p = 0; p < 2; ++p) {                              \
      const int row = (tid >> 4) + p * 32;                                       \
      const int col = (tid & 15) * 8;                                            \
      const size_t gr = (size_t)(b * Sq + n0 + row);                             \
      *(s16x8*)&Ks[row][col] = *(const s16x8*)&fused[gr * H6 + 4 * Hh + h * HD + col]; \
      *(s16x8*)&KRs[row][col] = *(const s16x8*)&qr[gr * Hh + h * HD + col];      \
    }                                                                            \
  }
#define STAGE_KKR(T)                                                             \
  {                                                                              \
    _Pragma("unroll") for (int p = 0; p < 2; ++p) {                              \
      const int row = (tid >> 4) + p * 32;                                       \
      const int col = (tid & 15) * 8;                                            \
      const size_t gr = (size_t)(b * Sq + (T) * 64 + row);                       \
      *(s16x8*)&Ks[row][col] = *(const s16x8*)&fused[gr * H6 + 5 * Hh + h * HD + col]; \
      *(s16x8*)&KRs[row][col] = *(const s16x8*)&kr[gr * Hh + h * HD + col];      \
    }                                                                            \
  }
#define STAGE_VT(T)                                                              \
  {                                                                              \
    _Pragma("unroll") for (int p = 0; p < 2; ++p) {                              \
      const int dd = (tid >> 3) + p * 64;                                        \
      const int mcol = (tid & 7) * 8;                                            \
      *(s16x8*)&Vt[dd][mcol] =                                                   \
          *(const s16x8*)&vt[(size_t)((b * NH + h) * HD + dd) * Sq + (T) * 64 + mcol]; \
    }                                                                            \
  }

  // ---- prologue: Q/QR through Ks/KRs, hoist 8 Q-frags (B-operand; layout == A)
  STAGE_QQR();
  __syncthreads();
  s16x8 qf[8];
  {
    const ushort_t(*Qsrc)[136] = t_w ? KRs : Ks;
#pragma unroll
    for (int ks = 0; ks < 8; ++ks)
      qf[ks] = *(const s16x8*)&Qsrc[nq * 32 + l31][ks * 16 + khalf * 8];
  }
  __syncthreads();
  STAGE_KKR(0);
  __syncthreads();

  f32x16v acc0 = {0.f, 0.f, 0.f, 0.f, 0.f, 0.f, 0.f, 0.f,
                  0.f, 0.f, 0.f, 0.f, 0.f, 0.f, 0.f, 0.f};  // plain
  f32x16v acc1 = acc0;                                       // rope
  f32x16v acc2 = acc0;                                       // ts

  const size_t tsrow = (size_t)(b * Sq + n0 + nh * 32 + l31) * Sq;
  const size_t mrow = (size_t)(b * Sq + n0 + nq * 32 + l31) * 64;  // u32 index base

  for (int t = 0; t < NT; ++t) {
    const int m0 = t * 64;
    // ---- phase 1: stage Vt(t), issue ts frags + mask bits, scores^T(t)
    STAGE_VT(t);
    s16x8 tsf[4];
#pragma unroll
    for (int ks = 0; ks < 4; ++ks)
      tsf[ks] = *(const s16x8*)&tsb[tsrow + m0 + ks * 16 + khalf * 8];
    const unsigned int bits = mbits32[mrow + t * 2 + mq];
    {
      const ushort_t(*Kmat)[136] = t_w ? KRs : Ks;
      f32x16v sacc = {0.f, 0.f, 0.f, 0.f, 0.f, 0.f, 0.f, 0.f,
                      0.f, 0.f, 0.f, 0.f, 0.f, 0.f, 0.f, 0.f};
#pragma unroll
      for (int ks = 0; ks < 8; ++ks) {
        s16x8 kf = *(const s16x8*)&Kmat[mq * 32 + l31][ks * 16 + khalf * 8];
        // SWAPPED: A = K-frag, B = Q-frag  =>  C = S^T (lane col = q-row n)
        sacc = __builtin_amdgcn_mfma_f32_32x32x16_bf16(kf, qf[ks], sacc, 0, 0, 0);
      }
      const int n_loc = nq * 32 + l31;
#pragma unroll
      for (int i = 0; i < 4; ++i) {
        float v[4];
#pragma unroll
        for (int j = 0; j < 4; ++j) {
          const int mu = 8 * i + 4 * khalf + j;  // m within 32-tile, row of S^T
          const float x = fmaxf(sacc[4 * i + j], 0.f) * ivs;
          v[j] = ((bits >> mu) & 1u) ? x : 0.f;
        }
        uint2 pk;
        pk.x = cvt_pk_bf16(v[0], v[1]);
        pk.y = cvt_pk_bf16(v[2], v[3]);
        *(uint2*)&Pl[t_w][n_loc][mq * 32 + 8 * i + 4 * khalf] = pk;
      }
    }
    __syncthreads();
    // ---- phase 2: stage K/KR(t+1), PV(t)
    if (t + 1 < NT) STAGE_KKR(t + 1);
#pragma unroll
    for (int ks = 0; ks < 4; ++ks) {
      s16x8 bV = *(const s16x8*)&Vt[dq * 32 + l31][ks * 16 + khalf * 8];
      s16x8 aP0 = *(const s16x8*)&Pl[0][nh * 32 + l31][ks * 16 + khalf * 8];
      s16x8 aP1 = *(const s16x8*)&Pl[1][nh * 32 + l31][ks * 16 + khalf * 8];
      acc0 = __builtin_amdgcn_mfma_f32_32x32x16_bf16(aP0, bV, acc0, 0, 0, 0);
      acc1 = __builtin_amdgcn_mfma_f32_32x32x16_bf16(aP1, bV, acc1, 0, 0, 0);
      acc2 = __builtin_amdgcn_mfma_f32_32x32x16_bf16(tsf[ks], bV, acc2, 0, 0, 0);
    }
    __syncthreads();
  }
#undef STAGE_QQR
#undef STAGE_KKR
#undef STAGE_VT

  // ---- epilogue: a2 = acc * gated. plain->+256, rope->+0, ts->+128
  const int dd = dq * 32 + l31;
#pragma unroll
  for (int r = 0; r < 16; ++r) {
    const int n = n0 + nh * 32 + (r & 3) + 8 * (r >> 2) + 4 * khalf;
    const size_t rowb = (size_t)(b * Sq + n);
    const int c_pl = h * 384 + 256 + dd;
    const int c_ro = h * 384 + 0 + dd;
    const int c_ts = h * 384 + 128 + dd;
    a2[rowb * H3 + c_pl] = f2bf(acc0[r] * bf2f(fused[rowb * H6 + c_pl]));
    a2[rowb * H3 + c_ro] = f2bf(acc1[r] * bf2f(fused[rowb * H6 + c_ro]));
    a2[rowb * H3 + c_ts] = f2bf(acc2[r] * bf2f(fused[rowb * H6 + c_ts]));
  }
}

// ---------------- RMS norm in-place
__global__ __launch_bounds__(256) void hstu_rms(float* __restrict__ y,
                                                const float* __restrict__ w) {
  __shared__ float red[4];
  const int row = blockIdx.x;
  const int tid = threadIdx.x;
  float4 v = *(float4*)&y[(size_t)row * Hh + tid * 4];
  float ss = v.x * v.x + v.y * v.y + v.z * v.z + v.w * v.w;
#pragma unroll
  for (int o = 32; o > 0; o >>= 1) ss += __shfl_down(ss, o);
  if ((tid & 63) == 0) red[tid >> 6] = ss;
  __syncthreads();
  const float tot = red[0] + red[1] + red[2] + red[3];
  const float r = 1.0f / sqrtf(tot / (float)Hh + 1e-6f);
  float4 wv = *(const float4*)&w[tid * 4];
  v.x *= r * wv.x;
  v.y *= r * wv.y;
  v.z *= r * wv.z;
  v.w *= r * wv.w;
  *(float4*)&y[(size_t)row * Hh + tid * 4] = v;
}

extern "C" void kernel_launch(void* const* d_in, const int* in_sizes, int n_in,
                              void* d_out, int out_size, void* d_ws, size_t ws_size,
                              hipStream_t stream) {
  const float* hidden = (const float*)d_in[0];
  const void* mask = d_in[1];
  const float* bias = (const float*)d_in[2];
  const float* Wqkvu = (const float*)d_in[3];
  const float* Wout = (const float*)d_in[4];
  const float* bout = (const float*)d_in[5];
  const float* rmsw = (const float*)d_in[6];
  float* out = (float*)d_out;
  float* ws = (float*)d_ws;

  ushort_t* fused = (ushort_t*)(ws + FUSED_OFF);
  ushort_t* a2 = (ushort_t*)(ws + A2_OFF);
  ushort_t* hb = (ushort_t*)(ws + HB_OFF);
  unsigned char* mbits = (unsigned char*)(ws + MBITS_OFF);  // overlays hb (dead after gemm_silu)
  ushort_t* wqt = (ushort_t*)(ws + WQT_OFF);
  ushort_t* wot = (ushort_t*)(ws + WOT_OFF);
  ushort_t* qrb = (ushort_t*)(ws + QR_OFF);
  ushort_t* krb = (ushort_t*)(ws + KR_OFF);
  ushort_t* vtb = (ushort_t*)(ws + VT_OFF);
  float* tab = ws + TAB_OFF;
  int* mflag = (int*)(ws + FLAG_OFF);
  ushort_t* tsbp = (ushort_t*)(ws + TSB_OFF);

  hstu_mask_detect<<<1, 256, 0, stream>>>((const unsigned int*)mask, mflag);
  hstu_tab<<<512, 256, 0, stream>>>(tab);
  hstu_cvt<<<4096, 256, 0, stream>>>(hidden, hb, (Bz * Sq * Hh) / 4);
  hstu_cvt_t<<<dim3(H6 / 32, Hh / 32), 256, 0, stream>>>(Wqkvu, wqt, Hh, H6);
  hstu_cvt_t<<<dim3(Hh / 32, H3 / 32), 256, 0, stream>>>(Wout, wot, H3, Hh);
  hstu_gemm_silu<<<dim3(H6 / 128, (Bz * Sq) / 128), 256, 0, stream>>>(hb, wqt, fused);
  // msk AFTER gemm_silu: mbits overlays hb
  hstu_msk<<<(Bz * Sq * Sq / 8) / 256, 256, 0, stream>>>(
      (const int*)mask, (const unsigned char*)mask, mflag, bias, tsbp, mbits);
  hstu_rope<<<(Bz * Sq * Hh / 8) / 256, 256, 0, stream>>>(fused, (const float2*)tab, qrb, krb);
  hstu_vt<<<dim3(Sq / 32, HD / 32, Bz * NH), 256, 0, stream>>>(fused, vtb);
  hstu_attn<<<dim3(NH, Sq / 64, Bz), 512, 0, stream>>>(
      fused, qrb, krb, vtb, tsbp, (const unsigned int*)mbits, a2);
  hstu_gemm_out<<<dim3(Hh / 64, (Bz * Sq) / 128), 256, 0, stream>>>(a2, wot, bout, hidden, out);
  hstu_rms<<<Bz * Sq, 256, 0, stream>>>(out, rmsw);
}

// Round 10
// 413.347 us; speedup vs baseline: 1.2294x; 1.2294x over previous
//
#include <hip/hip_runtime.h>
#include <math.h>

// Problem constants (B=2, S=2048, H=1024, NH=8, HD=128)
static constexpr int Bz = 2;
static constexpr int Sq = 2048;
static constexpr int Hh = 1024;
static constexpr int NH = 8;
static constexpr int HD = 128;
static constexpr int H3 = 3072;
static constexpr int H6 = 6144;

typedef unsigned short ushort_t;
typedef float f32x4v __attribute__((ext_vector_type(4)));
typedef float f32x16v __attribute__((ext_vector_type(16)));
typedef short s16x8 __attribute__((ext_vector_type(8)));

// Workspace layout in float units (×4 bytes). Peak ~146 MB.
static constexpr size_t FUSED_OFF = 0;          // bf16 [4096][6144] = 12,582,912 f
static constexpr size_t A2_OFF    = 12582912;   // bf16 [4096][3072] =  6,291,456 f
static constexpr size_t HB_OFF    = 18874368;   // bf16 [4096][1024] (dead after gemm_silu)
static constexpr size_t MBITS_OFF = 18874368;   // u8 [2][2048][256] = 1 MB (OVERLAYS hb)
static constexpr size_t WQT_OFF   = 20971520;   // bf16 [6144][1024] (dead after gemm_silu)
static constexpr size_t WOT_OFF   = 24117248;   // bf16 [1024][3072] =  1,572,864 f
static constexpr size_t QR_OFF    = 25690112;   // bf16 [4096][1024] =  2,097,152 f
static constexpr size_t KR_OFF    = 27787264;   // bf16 [4096][1024] =  2,097,152 f
static constexpr size_t VT_OFF    = 29884416;   // bf16 [16][128][2048] = 2,097,152 f
static constexpr size_t TAB_OFF   = 31981568;   // f32 S*64 float2 = 262,144 f
static constexpr size_t FLAG_OFF  = 32243712;   // 1 int (+pad)
static constexpr size_t TSB_OFF   = 32243716;   // bf16 [2][2048][2048] -> ends 36,438,020 f

__device__ __forceinline__ float silu_(float x) { return x / (1.0f + expf(-x)); }
__device__ __forceinline__ ushort_t f2bf(float x) {
  unsigned int u = __float_as_uint(x);
  u += 0x7fffu + ((u >> 16) & 1u);
  return (ushort_t)(u >> 16);
}
__device__ __forceinline__ float bf2f(ushort_t u) {
  return __uint_as_float(((unsigned int)u) << 16);
}
// pack two f32 -> u32 of 2 bf16 (RNE), no inline asm (m240: asm cvt_pk poisons regalloc)
__device__ __forceinline__ unsigned int pack_bf16(float lo, float hi) {
  return (unsigned int)f2bf(lo) | ((unsigned int)f2bf(hi) << 16);
}
__device__ __forceinline__ void g2l16(const ushort_t* g, ushort_t* l) {
  __builtin_amdgcn_global_load_lds(
      (const __attribute__((address_space(1))) unsigned int*)g,
      (__attribute__((address_space(3))) unsigned int*)l, 16, 0, 0);
}

// ---------------- mask dtype detect
__global__ __launch_bounds__(256) void hstu_mask_detect(const unsigned int* __restrict__ m,
                                                        int* __restrict__ flag) {
  __shared__ int s_any;
  if (threadIdx.x == 0) s_any = 0;
  __syncthreads();
  int any = 0;
  for (int i = threadIdx.x; i < 65536; i += 256)
    if (m[i] > 1u) any = 1;
  if (any) s_any = 1;
  __syncthreads();
  if (threadIdx.x == 0) *flag = s_any;
}

// ---------------- rope table
__global__ __launch_bounds__(256) void hstu_tab(float* __restrict__ tab) {
  int t = blockIdx.x * 256 + threadIdx.x;
  int i = t & 63;
  int s = t >> 6;
  float inv = powf(10000.0f, -(float)i / 64.0f);
  float sn, cs;
  sincosf((float)s * inv, &sn, &cs);
  tab[2 * t + 0] = cs;
  tab[2 * t + 1] = sn;
}

// ---------------- mask/bias precompute: tsb = bf16(mask?bias:0), mbits = bit-packed mask
__global__ __launch_bounds__(256) void hstu_msk(const int* __restrict__ mask32,
                                                const unsigned char* __restrict__ mask8,
                                                const int* __restrict__ mflag,
                                                const float* __restrict__ bias,
                                                ushort_t* __restrict__ tsb,
                                                unsigned char* __restrict__ mbits) {
  const size_t idx = (size_t)blockIdx.x * 256 + threadIdx.x;  // over B*S*S/8
  const size_t base = idx * 8;
  const int m_u8 = *mflag;
  int mk[8];
  if (m_u8) {
    uchar4 a = *(const uchar4*)&mask8[base];
    uchar4 b = *(const uchar4*)&mask8[base + 4];
    mk[0] = a.x; mk[1] = a.y; mk[2] = a.z; mk[3] = a.w;
    mk[4] = b.x; mk[5] = b.y; mk[6] = b.z; mk[7] = b.w;
  } else {
    int4 a = *(const int4*)&mask32[base];
    int4 b = *(const int4*)&mask32[base + 4];
    mk[0] = a.x; mk[1] = a.y; mk[2] = a.z; mk[3] = a.w;
    mk[4] = b.x; mk[5] = b.y; mk[6] = b.z; mk[7] = b.w;
  }
  float4 b0 = *(const float4*)&bias[base];
  float4 b1 = *(const float4*)&bias[base + 4];
  float bb[8] = {b0.x, b0.y, b0.z, b0.w, b1.x, b1.y, b1.z, b1.w};
  ushort_t ts[8];
  unsigned int byte = 0;
#pragma unroll
  for (int i = 0; i < 8; ++i) {
    ts[i] = f2bf(mk[i] ? bb[i] : 0.0f);
    byte |= (mk[i] ? 1u : 0u) << i;
  }
  *(s16x8*)&tsb[base] = *(s16x8*)ts;
  mbits[idx] = (unsigned char)byte;
}

// ---------------- f32 -> bf16 copy (hidden)
__global__ __launch_bounds__(256) void hstu_cvt(const float* __restrict__ in,
                                                ushort_t* __restrict__ out, int n4) {
  int i = blockIdx.x * 256 + threadIdx.x;
  if (i >= n4) return;
  float4 v = *(const float4*)&in[(size_t)i * 4];
  ushort4 o;
  o.x = f2bf(v.x); o.y = f2bf(v.y); o.z = f2bf(v.z); o.w = f2bf(v.w);
  *(ushort4*)&out[(size_t)i * 4] = o;
}

// ---------------- f32 [K][N] -> bf16 [N][K] transpose-convert (weights)
__global__ __launch_bounds__(256) void hstu_cvt_t(const float* __restrict__ in,
                                                  ushort_t* __restrict__ out, int K, int N) {
  __shared__ float t[32][33];
  const int n0 = blockIdx.x * 32, k0 = blockIdx.y * 32;
  const int c = threadIdx.x & 31, rr = threadIdx.x >> 5;
#pragma unroll
  for (int p = 0; p < 4; ++p)
    t[rr + p * 8][c] = in[(size_t)(k0 + rr + p * 8) * N + n0 + c];
  __syncthreads();
#pragma unroll
  for (int p = 0; p < 4; ++p)
    out[(size_t)(n0 + rr + p * 8) * K + k0 + c] = f2bf(t[c][rr + p * 8]);
}

// ---------------- rope precompute
__global__ __launch_bounds__(256) void hstu_rope(const ushort_t* __restrict__ fused,
                                                 const float2* __restrict__ tab,
                                                 ushort_t* __restrict__ qr,
                                                 ushort_t* __restrict__ kr) {
  const int idx = blockIdx.x * 256 + threadIdx.x;
  const int row = idx >> 7;
  const int cg = (idx & 127) * 8;
  const int s = row & (Sq - 1);
  const float2* trow = &tab[(size_t)s * 64 + ((cg & 127) >> 1)];
  float2 t[4];
#pragma unroll
  for (int p = 0; p < 4; ++p) t[p] = trow[p];

  s16x8 q8 = *(const s16x8*)&fused[(size_t)row * H6 + 4 * Hh + cg];
  s16x8 k8 = *(const s16x8*)&fused[(size_t)row * H6 + 5 * Hh + cg];
  ushort_t qo[8], ko[8];
#pragma unroll
  for (int p = 0; p < 4; ++p) {
    float qx = bf2f((ushort_t)q8[2 * p]), qy = bf2f((ushort_t)q8[2 * p + 1]);
    float kx = bf2f((ushort_t)k8[2 * p]), ky = bf2f((ushort_t)k8[2 * p + 1]);
    qo[2 * p] = f2bf(qx * t[p].x - qy * t[p].y);
    qo[2 * p + 1] = f2bf(qy * t[p].x + qx * t[p].y);
    ko[2 * p] = f2bf(kx * t[p].x - ky * t[p].y);
    ko[2 * p + 1] = f2bf(ky * t[p].x + kx * t[p].y);
  }
  *(s16x8*)&qr[(size_t)row * Hh + cg] = *(s16x8*)qo;
  *(s16x8*)&kr[(size_t)row * Hh + cg] = *(s16x8*)ko;
}

// ---------------- V transpose precompute
__global__ __launch_bounds__(256) void hstu_vt(const ushort_t* __restrict__ fused,
                                               ushort_t* __restrict__ vt) {
  __shared__ ushort_t t[32][36];
  const int m0 = blockIdx.x * 32, d0 = blockIdx.y * 32, bh = blockIdx.z;
  const int b = bh >> 3, h = bh & 7;
  const int r = threadIdx.x >> 3, cg = (threadIdx.x & 7) * 4;
  *(ushort4*)&t[r][cg] =
      *(const ushort4*)&fused[(size_t)(b * Sq + m0 + r) * H6 + 3 * Hh + h * HD + d0 + cg];
  __syncthreads();
  ushort4 o;
  o.x = t[cg + 0][r]; o.y = t[cg + 1][r]; o.z = t[cg + 2][r]; o.w = t[cg + 3][r];
  *(ushort4*)&vt[(size_t)(bh * HD + d0 + r) * Sq + m0 + cg] = o;
}

// ---------------- GEMM1: fused = silu(hidden_bf @ WqT^T)  bf16 out
__global__ __launch_bounds__(256) void hstu_gemm_silu(const ushort_t* __restrict__ A,
                                                      const ushort_t* __restrict__ Bt,
                                                      ushort_t* __restrict__ C) {
  constexpr int K = 1024, N = H6;
  __shared__ ushort_t As[128 * 64];
  __shared__ ushort_t Bs[128 * 64];
  const int tid = threadIdx.x, lane = tid & 63, wid = tid >> 6;
  const int lo4 = lane & 15, hi2 = lane >> 4;
  const int wr = wid >> 1, wc = wid & 1;
  const int row0 = blockIdx.y * 128, col0 = blockIdx.x * 128;
  const int srow = lane >> 3, scol = (lane & 7) * 8;
  f32x4v acc[4][4];
#pragma unroll
  for (int i = 0; i < 4; ++i)
#pragma unroll
    for (int j = 0; j < 4; ++j) acc[i][j] = {0.f, 0.f, 0.f, 0.f};

  for (int k0 = 0; k0 < K; k0 += 64) {
    __syncthreads();
#pragma unroll
    for (int i = 0; i < 4; ++i) {
      const int rb = wid * 32 + i * 8;
      g2l16(&A[(size_t)(row0 + rb + srow) * K + k0 + scol], &As[rb * 64]);
      g2l16(&Bt[(size_t)(col0 + rb + srow) * K + k0 + scol], &Bs[rb * 64]);
    }
    __syncthreads();
#pragma unroll
    for (int kc = 0; kc < 2; ++kc) {
      s16x8 af[4], bfr[4];
#pragma unroll
      for (int mi = 0; mi < 4; ++mi)
        af[mi] = *(const s16x8*)&As[(wr * 64 + mi * 16 + lo4) * 64 + kc * 32 + hi2 * 8];
#pragma unroll
      for (int nj = 0; nj < 4; ++nj)
        bfr[nj] = *(const s16x8*)&Bs[(wc * 64 + nj * 16 + lo4) * 64 + kc * 32 + hi2 * 8];
#pragma unroll
      for (int mi = 0; mi < 4; ++mi)
#pragma unroll
        for (int nj = 0; nj < 4; ++nj)
          acc[mi][nj] = __builtin_amdgcn_mfma_f32_16x16x32_bf16(af[mi], bfr[nj], acc[mi][nj], 0, 0, 0);
    }
  }
#pragma unroll
  for (int mi = 0; mi < 4; ++mi)
#pragma unroll
    for (int nj = 0; nj < 4; ++nj)
#pragma unroll
      for (int r = 0; r < 4; ++r) {
        const int row = row0 + wr * 64 + mi * 16 + hi2 * 4 + r;
        const int col = col0 + wc * 64 + nj * 16 + lo4;
        C[(size_t)row * N + col] = f2bf(silu_(acc[mi][nj][r]));
      }
}

// ---------------- GEMM2: out = A2 @ WoT^T + b_out + hidden  f32 out
__global__ __launch_bounds__(256) void hstu_gemm_out(const ushort_t* __restrict__ A,
                                                     const ushort_t* __restrict__ Bt,
                                                     const float* __restrict__ bout,
                                                     const float* __restrict__ hidden,
                                                     float* __restrict__ C) {
  constexpr int K = H3, N = Hh;
  __shared__ ushort_t As[128 * 64];
  __shared__ ushort_t Bs[64 * 64];
  const int tid = threadIdx.x, lane = tid & 63, wid = tid >> 6;
  const int lo4 = lane & 15, hi2 = lane >> 4;
  const int wr = wid >> 1, wc = wid & 1;
  const int row0 = blockIdx.y * 128, col0 = blockIdx.x * 64;
  const int srow = lane >> 3, scol = (lane & 7) * 8;
  f32x4v acc[4][2];
#pragma unroll
  for (int i = 0; i < 4; ++i)
#pragma unroll
    for (int j = 0; j < 2; ++j) acc[i][j] = {0.f, 0.f, 0.f, 0.f};

  for (int k0 = 0; k0 < K; k0 += 64) {
    __syncthreads();
#pragma unroll
    for (int i = 0; i < 4; ++i) {
      const int rb = wid * 32 + i * 8;
      g2l16(&A[(size_t)(row0 + rb + srow) * K + k0 + scol], &As[rb * 64]);
    }
#pragma unroll
    for (int i = 0; i < 2; ++i) {
      const int rb = wid * 16 + i * 8;
      g2l16(&Bt[(size_t)(col0 + rb + srow) * K + k0 + scol], &Bs[rb * 64]);
    }
    __syncthreads();
#pragma unroll
    for (int kc = 0; kc < 2; ++kc) {
      s16x8 af[4], bfr[2];
#pragma unroll
      for (int mi = 0; mi < 4; ++mi)
        af[mi] = *(const s16x8*)&As[(wr * 64 + mi * 16 + lo4) * 64 + kc * 32 + hi2 * 8];
#pragma unroll
      for (int nj = 0; nj < 2; ++nj)
        bfr[nj] = *(const s16x8*)&Bs[(wc * 32 + nj * 16 + lo4) * 64 + kc * 32 + hi2 * 8];
#pragma unroll
      for (int mi = 0; mi < 4; ++mi)
#pragma unroll
        for (int nj = 0; nj < 2; ++nj)
          acc[mi][nj] = __builtin_amdgcn_mfma_f32_16x16x32_bf16(af[mi], bfr[nj], acc[mi][nj], 0, 0, 0);
    }
  }
#pragma unroll
  for (int mi = 0; mi < 4; ++mi)
#pragma unroll
    for (int nj = 0; nj < 2; ++nj)
#pragma unroll
      for (int r = 0; r < 4; ++r) {
        const int row = row0 + wr * 64 + mi * 16 + hi2 * 4 + r;
        const int col = col0 + wc * 32 + nj * 16 + lo4;
        C[(size_t)row * N + col] = acc[mi][nj][r] + bout[col] + hidden[(size_t)row * N + col];
      }
}

// ---------------- fused attention, bf16 mfma_32x32x16, SWAPPED scores (S^T = K x Q).
// Block: (h, nblock, b), 8 waves, QBLK=64, KVBLK=64, 2 barriers/iter.
// Phase 1: Vt stage + scores^T (bitmask in-register, packed b64 Pl writes).
// Phase 2: K/KR stage(t+1) + tsf loads (L2) + PV.
__global__ __launch_bounds__(512, 4) void hstu_attn(const ushort_t* __restrict__ fused,
                                                    const ushort_t* __restrict__ qr,
                                                    const ushort_t* __restrict__ kr,
                                                    const ushort_t* __restrict__ vt,
                                                    const ushort_t* __restrict__ tsb,
                                                    const unsigned int* __restrict__ mbits32,
                                                    ushort_t* __restrict__ a2) {
  __shared__ __align__(16) ushort_t Ks[64][136];        // K (also Q in prologue)
  __shared__ __align__(16) ushort_t KRs[64][136];       // roped K (also roped Q)
  __shared__ __align__(16) ushort_t Vt[128][72];        // Vt[dd][m]
  __shared__ __align__(16) ushort_t Pl[2][64][72];      // 0=plain 1=rope

  const int tid = threadIdx.x;
  const int lane = tid & 63;
  const int wid = tid >> 6;   // 0..7
  const int l31 = lane & 31;
  const int khalf = lane >> 5;  // 0/1
  const int h = blockIdx.x;     // head-first -> XCD pinning
  const int n0 = blockIdx.y * 64;
  const int b = blockIdx.z;
  const float ivs = 1.0f / 2048.0f;
  constexpr int NT = Sq / 64;

  // score role: type, n-quarter(32), m-tile(32)
  const int t_w = wid >> 2;
  const int nq = (wid >> 1) & 1;
  const int mq = wid & 1;
  // PV role: n-half(32 rows), dd-quarter(32)
  const int nh = wid & 1;
  const int dq = wid >> 1;

#define STAGE_QQR()                                                              \
  {                                                                              \
    _Pragma("unroll") for (int p = 0; p < 2; ++p) {                              \
      const int row = (tid >> 4) + p * 32;                                       \
      const int col = (tid & 15) * 8;                                            \
      const size_t gr = (size_t)(b * Sq + n0 + row);                             \
      *(s16x8*)&Ks[row][col] = *(const s16x8*)&fused[gr * H6 + 4 * Hh + h * HD + col]; \
      *(s16x8*)&KRs[row][col] = *(const s16x8*)&qr[gr * Hh + h * HD + col];      \
    }                                                                            \
  }
#define STAGE_KKR(T)                                                             \
  {                                                                              \
    _Pragma("unroll") for (int p = 0; p < 2; ++p) {                              \
      const int row = (tid >> 4) + p * 32;                                       \
      const int col = (tid & 15) * 8;                                            \
      const size_t gr = (size_t)(b * Sq + (T) * 64 + row);                       \
      *(s16x8*)&Ks[row][col] = *(const s16x8*)&fused[gr * H6 + 5 * Hh + h * HD + col]; \
      *(s16x8*)&KRs[row][col] = *(const s16x8*)&kr[gr * Hh + h * HD + col];      \
    }                                                                            \
  }
#define STAGE_VT(T)                                                              \
  {                                                                              \
    _Pragma("unroll") for (int p = 0; p < 2; ++p) {                              \
      const int dd = (tid >> 3) + p * 64;                                        \
      const int mcol = (tid & 7) * 8;                                            \
      *(s16x8*)&Vt[dd][mcol] =                                                   \
          *(const s16x8*)&vt[(size_t)((b * NH + h) * HD + dd) * Sq + (T) * 64 + mcol]; \
    }                                                                            \
  }

  // ---- prologue: Q/QR through Ks/KRs, hoist 8 Q-frags (B-operand; layout == A)
  STAGE_QQR();
  __syncthreads();
  s16x8 qf[8];
  {
    const ushort_t(*Qsrc)[136] = t_w ? KRs : Ks;
#pragma unroll
    for (int ks = 0; ks < 8; ++ks)
      qf[ks] = *(const s16x8*)&Qsrc[nq * 32 + l31][ks * 16 + khalf * 8];
  }
  __syncthreads();
  STAGE_KKR(0);
  __syncthreads();

  f32x16v acc0 = {0.f, 0.f, 0.f, 0.f, 0.f, 0.f, 0.f, 0.f,
                  0.f, 0.f, 0.f, 0.f, 0.f, 0.f, 0.f, 0.f};  // plain
  f32x16v acc1 = acc0;                                       // rope
  f32x16v acc2 = acc0;                                       // ts

  const size_t tsrow = (size_t)(b * Sq + n0 + nh * 32 + l31) * Sq;
  const size_t mrow = (size_t)(b * Sq + n0 + nq * 32 + l31) * 64;  // u32 index base

  for (int t = 0; t < NT; ++t) {
    const int m0 = t * 64;
    // ---- phase 1: stage Vt(t), scores^T(t) with in-register mask
    STAGE_VT(t);
    const unsigned int bits = mbits32[mrow + t * 2 + mq];
    {
      const ushort_t(*Kmat)[136] = t_w ? KRs : Ks;
      f32x16v sacc = {0.f, 0.f, 0.f, 0.f, 0.f, 0.f, 0.f, 0.f,
                      0.f, 0.f, 0.f, 0.f, 0.f, 0.f, 0.f, 0.f};
#pragma unroll
      for (int ks = 0; ks < 8; ++ks) {
        s16x8 kf = *(const s16x8*)&Kmat[mq * 32 + l31][ks * 16 + khalf * 8];
        // SWAPPED: A = K-frag, B = Q-frag  =>  C = S^T (lane col = q-row n)
        sacc = __builtin_amdgcn_mfma_f32_32x32x16_bf16(kf, qf[ks], sacc, 0, 0, 0);
      }
      const int n_loc = nq * 32 + l31;
#pragma unroll
      for (int i = 0; i < 4; ++i) {
        float v0 = fmaxf(sacc[4 * i + 0], 0.f) * ivs;
        float v1 = fmaxf(sacc[4 * i + 1], 0.f) * ivs;
        float v2 = fmaxf(sacc[4 * i + 2], 0.f) * ivs;
        float v3 = fmaxf(sacc[4 * i + 3], 0.f) * ivs;
        const int mu = 8 * i + 4 * khalf;  // m within 32-tile (row of S^T)
        v0 = ((bits >> (mu + 0)) & 1u) ? v0 : 0.f;
        v1 = ((bits >> (mu + 1)) & 1u) ? v1 : 0.f;
        v2 = ((bits >> (mu + 2)) & 1u) ? v2 : 0.f;
        v3 = ((bits >> (mu + 3)) & 1u) ? v3 : 0.f;
        uint2 pk;
        pk.x = pack_bf16(v0, v1);
        pk.y = pack_bf16(v2, v3);
        *(uint2*)&Pl[t_w][n_loc][mq * 32 + mu] = pk;
      }
    }
    __syncthreads();
    // ---- phase 2: stage K/KR(t+1), tsf loads (L2-warm), PV(t)
    if (t + 1 < NT) STAGE_KKR(t + 1);
#pragma unroll
    for (int ks = 0; ks < 4; ++ks) {
      s16x8 tsf = *(const s16x8*)&tsb[tsrow + m0 + ks * 16 + khalf * 8];
      s16x8 bV = *(const s16x8*)&Vt[dq * 32 + l31][ks * 16 + khalf * 8];
      s16x8 aP0 = *(const s16x8*)&Pl[0][nh * 32 + l31][ks * 16 + khalf * 8];
      s16x8 aP1 = *(const s16x8*)&Pl[1][nh * 32 + l31][ks * 16 + khalf * 8];
      acc0 = __builtin_amdgcn_mfma_f32_32x32x16_bf16(aP0, bV, acc0, 0, 0, 0);
      acc1 = __builtin_amdgcn_mfma_f32_32x32x16_bf16(aP1, bV, acc1, 0, 0, 0);
      acc2 = __builtin_amdgcn_mfma_f32_32x32x16_bf16(tsf, bV, acc2, 0, 0, 0);
    }
    __syncthreads();
  }
#undef STAGE_QQR
#undef STAGE_KKR
#undef STAGE_VT

  // ---- epilogue: a2 = acc * gated. plain->+256, rope->+0, ts->+128
  const int dd = dq * 32 + l31;
#pragma unroll
  for (int r = 0; r < 16; ++r) {
    const int n = n0 + nh * 32 + (r & 3) + 8 * (r >> 2) + 4 * khalf;
    const size_t rowb = (size_t)(b * Sq + n);
    const int c_pl = h * 384 + 256 + dd;
    const int c_ro = h * 384 + 0 + dd;
    const int c_ts = h * 384 + 128 + dd;
    a2[rowb * H3 + c_pl] = f2bf(acc0[r] * bf2f(fused[rowb * H6 + c_pl]));
    a2[rowb * H3 + c_ro] = f2bf(acc1[r] * bf2f(fused[rowb * H6 + c_ro]));
    a2[rowb * H3 + c_ts] = f2bf(acc2[r] * bf2f(fused[rowb * H6 + c_ts]));
  }
}

// ---------------- RMS norm in-place
__global__ __launch_bounds__(256) void hstu_rms(float* __restrict__ y,
                                                const float* __restrict__ w) {
  __shared__ float red[4];
  const int row = blockIdx.x;
  const int tid = threadIdx.x;
  float4 v = *(float4*)&y[(size_t)row * Hh + tid * 4];
  float ss = v.x * v.x + v.y * v.y + v.z * v.z + v.w * v.w;
#pragma unroll
  for (int o = 32; o > 0; o >>= 1) ss += __shfl_down(ss, o);
  if ((tid & 63) == 0) red[tid >> 6] = ss;
  __syncthreads();
  const float tot = red[0] + red[1] + red[2] + red[3];
  const float r = 1.0f / sqrtf(tot / (float)Hh + 1e-6f);
  float4 wv = *(const float4*)&w[tid * 4];
  v.x *= r * wv.x;
  v.y *= r * wv.y;
  v.z *= r * wv.z;
  v.w *= r * wv.w;
  *(float4*)&y[(size_t)row * Hh + tid * 4] = v;
}

extern "C" void kernel_launch(void* const* d_in, const int* in_sizes, int n_in,
                              void* d_out, int out_size, void* d_ws, size_t ws_size,
                              hipStream_t stream) {
  const float* hidden = (const float*)d_in[0];
  const void* mask = d_in[1];
  const float* bias = (const float*)d_in[2];
  const float* Wqkvu = (const float*)d_in[3];
  const float* Wout = (const float*)d_in[4];
  const float* bout = (const float*)d_in[5];
  const float* rmsw = (const float*)d_in[6];
  float* out = (float*)d_out;
  float* ws = (float*)d_ws;

  ushort_t* fused = (ushort_t*)(ws + FUSED_OFF);
  ushort_t* a2 = (ushort_t*)(ws + A2_OFF);
  ushort_t* hb = (ushort_t*)(ws + HB_OFF);
  unsigned char* mbits = (unsigned char*)(ws + MBITS_OFF);  // overlays hb (dead after gemm_silu)
  ushort_t* wqt = (ushort_t*)(ws + WQT_OFF);
  ushort_t* wot = (ushort_t*)(ws + WOT_OFF);
  ushort_t* qrb = (ushort_t*)(ws + QR_OFF);
  ushort_t* krb = (ushort_t*)(ws + KR_OFF);
  ushort_t* vtb = (ushort_t*)(ws + VT_OFF);
  float* tab = ws + TAB_OFF;
  int* mflag = (int*)(ws + FLAG_OFF);
  ushort_t* tsbp = (ushort_t*)(ws + TSB_OFF);

  hstu_mask_detect<<<1, 256, 0, stream>>>((const unsigned int*)mask, mflag);
  hstu_tab<<<512, 256, 0, stream>>>(tab);
  hstu_cvt<<<4096, 256, 0, stream>>>(hidden, hb, (Bz * Sq * Hh) / 4);
  hstu_cvt_t<<<dim3(H6 / 32, Hh / 32), 256, 0, stream>>>(Wqkvu, wqt, Hh, H6);
  hstu_cvt_t<<<dim3(Hh / 32, H3 / 32), 256, 0, stream>>>(Wout, wot, H3, Hh);
  hstu_gemm_silu<<<dim3(H6 / 128, (Bz * Sq) / 128), 256, 0, stream>>>(hb, wqt, fused);
  // msk AFTER gemm_silu: mbits overlays hb
  hstu_msk<<<(Bz * Sq * Sq / 8) / 256, 256, 0, stream>>>(
      (const int*)mask, (const unsigned char*)mask, mflag, bias, tsbp, mbits);
  hstu_rope<<<(Bz * Sq * Hh / 8) / 256, 256, 0, stream>>>(fused, (const float2*)tab, qrb, krb);
  hstu_vt<<<dim3(Sq / 32, HD / 32, Bz * NH), 256, 0, stream>>>(fused, vtb);
  hstu_attn<<<dim3(NH, Sq / 64, Bz), 512, 0, stream>>>(
      fused, qrb, krb, vtb, tsbp, (const unsigned int*)mbits, a2);
  hstu_gemm_out<<<dim3(Hh / 64, (Bz * Sq) / 128), 256, 0, stream>>>(a2, wot, bout, hidden, out);
  hstu_rms<<<Bz * Sq, 256, 0, stream>>>(out, rmsw);
}

// Round 11
// 370.884 us; speedup vs baseline: 1.3702x; 1.1145x over previous
//
#include <hip/hip_runtime.h>
#include <math.h>

// Problem constants (B=2, S=2048, H=1024, NH=8, HD=128)
static constexpr int Bz = 2;
static constexpr int Sq = 2048;
static constexpr int Hh = 1024;
static constexpr int NH = 8;
static constexpr int HD = 128;
static constexpr int H3 = 3072;
static constexpr int H6 = 6144;

typedef unsigned short ushort_t;
typedef float f32x4v __attribute__((ext_vector_type(4)));
typedef short s16x8 __attribute__((ext_vector_type(8)));

// Workspace layout in float units (×4 bytes). Peak requirement ~146 MB.
static constexpr size_t FUSED_OFF = 0;          // bf16 [4096][6144] = 12,582,912 f
static constexpr size_t A2_OFF    = 12582912;   // bf16 [4096][3072] =  6,291,456 f
static constexpr size_t HB_OFF    = 18874368;   // bf16 [4096][1024] (dead after gemm_silu)
static constexpr size_t MTB_OFF   = 18874368;   // bf16 [2][2048][2048] (OVERLAYS hb+wqt)
static constexpr size_t WQT_OFF   = 20971520;   // bf16 [6144][1024] (dead after gemm_silu)
static constexpr size_t WOT_OFF   = 24117248;   // bf16 [1024][3072] =  1,572,864 f
static constexpr size_t QR_OFF    = 25690112;   // bf16 [4096][1024] =  2,097,152 f
static constexpr size_t KR_OFF    = 27787264;   // bf16 [4096][1024] =  2,097,152 f
static constexpr size_t VT_OFF    = 29884416;   // bf16 [16][128][2048] = 2,097,152 f
static constexpr size_t TAB_OFF   = 31981568;   // f32 S*64 float2 = 262,144 f
static constexpr size_t FLAG_OFF  = 32243712;   // 1 int (+pad)
static constexpr size_t TSB_OFF   = 32243716;   // bf16 [2][2048][2048] -> ends 36,438,020 f

__device__ __forceinline__ float silu_(float x) { return x / (1.0f + expf(-x)); }
__device__ __forceinline__ ushort_t f2bf(float x) {
  unsigned int u = __float_as_uint(x);
  u += 0x7fffu + ((u >> 16) & 1u);
  return (ushort_t)(u >> 16);
}
__device__ __forceinline__ float bf2f(ushort_t u) {
  return __uint_as_float(((unsigned int)u) << 16);
}
// async global->LDS 16B: per-lane global src, wave-uniform LDS base (+lane*16B by HW)
__device__ __forceinline__ void g2l16(const ushort_t* g, ushort_t* l) {
  __builtin_amdgcn_global_load_lds(
      (const __attribute__((address_space(1))) unsigned int*)g,
      (__attribute__((address_space(3))) unsigned int*)l, 16, 0, 0);
}

// ---------------- mask dtype detect: any 32-bit word > 1 => byte-packed bools
__global__ __launch_bounds__(256) void hstu_mask_detect(const unsigned int* __restrict__ m,
                                                        int* __restrict__ flag) {
  __shared__ int s_any;
  if (threadIdx.x == 0) s_any = 0;
  __syncthreads();
  int any = 0;
  for (int i = threadIdx.x; i < 65536; i += 256)
    if (m[i] > 1u) any = 1;
  if (any) s_any = 1;
  __syncthreads();
  if (threadIdx.x == 0) *flag = s_any;
}

// ---------------- rope table: tab[s*64+i] = {cos,sin}(s * 10000^(-i/64))
__global__ __launch_bounds__(256) void hstu_tab(float* __restrict__ tab) {
  int t = blockIdx.x * 256 + threadIdx.x;
  int i = t & 63;
  int s = t >> 6;
  float inv = powf(10000.0f, -(float)i / 64.0f);
  float sn, cs;
  sincosf((float)s * inv, &sn, &cs);
  tab[2 * t + 0] = cs;
  tab[2 * t + 1] = sn;
}

// ---------------- mask/bias precompute: tsb = bf16(mask?bias:0), mtb = bf16(mask?1:0)
__global__ __launch_bounds__(256) void hstu_msk(const int* __restrict__ mask32,
                                                const unsigned char* __restrict__ mask8,
                                                const int* __restrict__ mflag,
                                                const float* __restrict__ bias,
                                                ushort_t* __restrict__ tsb,
                                                ushort_t* __restrict__ mtb) {
  const size_t base = ((size_t)blockIdx.x * 256 + threadIdx.x) * 8;  // over B*S*S
  const int m_u8 = *mflag;
  int mk[8];
  if (m_u8) {
    uchar4 a = *(const uchar4*)&mask8[base];
    uchar4 b = *(const uchar4*)&mask8[base + 4];
    mk[0] = a.x; mk[1] = a.y; mk[2] = a.z; mk[3] = a.w;
    mk[4] = b.x; mk[5] = b.y; mk[6] = b.z; mk[7] = b.w;
  } else {
    int4 a = *(const int4*)&mask32[base];
    int4 b = *(const int4*)&mask32[base + 4];
    mk[0] = a.x; mk[1] = a.y; mk[2] = a.z; mk[3] = a.w;
    mk[4] = b.x; mk[5] = b.y; mk[6] = b.z; mk[7] = b.w;
  }
  float4 b0 = *(const float4*)&bias[base];
  float4 b1 = *(const float4*)&bias[base + 4];
  float bb[8] = {b0.x, b0.y, b0.z, b0.w, b1.x, b1.y, b1.z, b1.w};
  ushort_t ts[8], mt[8];
#pragma unroll
  for (int i = 0; i < 8; ++i) {
    ts[i] = f2bf(mk[i] ? bb[i] : 0.0f);
    mt[i] = mk[i] ? 0x3f80u : 0u;
  }
  *(s16x8*)&tsb[base] = *(s16x8*)ts;
  *(s16x8*)&mtb[base] = *(s16x8*)mt;
}

// ---------------- f32 -> bf16 row-major copy (hidden)
__global__ __launch_bounds__(256) void hstu_cvt(const float* __restrict__ in,
                                                ushort_t* __restrict__ out, int n4) {
  int i = blockIdx.x * 256 + threadIdx.x;
  if (i >= n4) return;
  float4 v = *(const float4*)&in[(size_t)i * 4];
  ushort4 o;
  o.x = f2bf(v.x); o.y = f2bf(v.y); o.z = f2bf(v.z); o.w = f2bf(v.w);
  *(ushort4*)&out[(size_t)i * 4] = o;
}

// ---------------- f32 [K][N] -> bf16 [N][K] transpose-convert (weights)
__global__ __launch_bounds__(256) void hstu_cvt_t(const float* __restrict__ in,
                                                  ushort_t* __restrict__ out, int K, int N) {
  __shared__ float t[32][33];
  const int n0 = blockIdx.x * 32, k0 = blockIdx.y * 32;
  const int c = threadIdx.x & 31, rr = threadIdx.x >> 5;
#pragma unroll
  for (int p = 0; p < 4; ++p)
    t[rr + p * 8][c] = in[(size_t)(k0 + rr + p * 8) * N + n0 + c];
  __syncthreads();
#pragma unroll
  for (int p = 0; p < 4; ++p)
    out[(size_t)(n0 + rr + p * 8) * K + k0 + c] = f2bf(t[c][rr + p * 8]);
}

// ---------------- rope precompute: qr/kr[b][s][h*128+d] = rope(fused q/k), bf16
__global__ __launch_bounds__(256) void hstu_rope(const ushort_t* __restrict__ fused,
                                                 const float2* __restrict__ tab,
                                                 ushort_t* __restrict__ qr,
                                                 ushort_t* __restrict__ kr) {
  const int idx = blockIdx.x * 256 + threadIdx.x;  // over 4096*1024/8
  const int row = idx >> 7;
  const int cg = (idx & 127) * 8;
  const int s = row & (Sq - 1);
  const float2* trow = &tab[(size_t)s * 64 + ((cg & 127) >> 1)];
  float2 t[4];
#pragma unroll
  for (int p = 0; p < 4; ++p) t[p] = trow[p];

  s16x8 q8 = *(const s16x8*)&fused[(size_t)row * H6 + 4 * Hh + cg];
  s16x8 k8 = *(const s16x8*)&fused[(size_t)row * H6 + 5 * Hh + cg];
  ushort_t qo[8], ko[8];
#pragma unroll
  for (int p = 0; p < 4; ++p) {
    float qx = bf2f((ushort_t)q8[2 * p]), qy = bf2f((ushort_t)q8[2 * p + 1]);
    float kx = bf2f((ushort_t)k8[2 * p]), ky = bf2f((ushort_t)k8[2 * p + 1]);
    qo[2 * p] = f2bf(qx * t[p].x - qy * t[p].y);
    qo[2 * p + 1] = f2bf(qy * t[p].x + qx * t[p].y);
    ko[2 * p] = f2bf(kx * t[p].x - ky * t[p].y);
    ko[2 * p + 1] = f2bf(ky * t[p].x + kx * t[p].y);
  }
  *(s16x8*)&qr[(size_t)row * Hh + cg] = *(s16x8*)qo;
  *(s16x8*)&kr[(size_t)row * Hh + cg] = *(s16x8*)ko;
}

// ---------------- V transpose precompute: vt[(b*8+h)*128+dd][m] = V[b][m][h*128+dd]
__global__ __launch_bounds__(256) void hstu_vt(const ushort_t* __restrict__ fused,
                                               ushort_t* __restrict__ vt) {
  __shared__ ushort_t t[32][36];
  const int m0 = blockIdx.x * 32, d0 = blockIdx.y * 32, bh = blockIdx.z;
  const int b = bh >> 3, h = bh & 7;
  const int r = threadIdx.x >> 3, cg = (threadIdx.x & 7) * 4;
  *(ushort4*)&t[r][cg] =
      *(const ushort4*)&fused[(size_t)(b * Sq + m0 + r) * H6 + 3 * Hh + h * HD + d0 + cg];
  __syncthreads();
  ushort4 o;
  o.x = t[cg + 0][r]; o.y = t[cg + 1][r]; o.z = t[cg + 2][r]; o.w = t[cg + 3][r];
  *(ushort4*)&vt[(size_t)(bh * HD + d0 + r) * Sq + m0 + cg] = o;
}

// ---------------- GEMM1: fused = silu(hidden_bf @ WqT^T)  M=4096 N=6144 K=1024, bf16 out
// T1: bijective XCD swizzle — each XCD owns contiguous output rows (A-panel L2 locality).
__global__ __launch_bounds__(256) void hstu_gemm_silu(const ushort_t* __restrict__ A,
                                                      const ushort_t* __restrict__ Bt,
                                                      ushort_t* __restrict__ C) {
  constexpr int K = 1024, N = H6;
  __shared__ ushort_t As[128 * 64];
  __shared__ ushort_t Bs[128 * 64];
  const int tid = threadIdx.x, lane = tid & 63, wid = tid >> 6;
  const int lo4 = lane & 15, hi2 = lane >> 4;
  const int wr = wid >> 1, wc = wid & 1;
  // XCD swizzle: nwg = 48*32 = 1536 (%8==0 -> bijective)
  const int gx = gridDim.x;
  const int lin = blockIdx.y * gx + blockIdx.x;
  const int cpx = (gx * gridDim.y) >> 3;
  const int swz = (lin & 7) * cpx + (lin >> 3);
  const int row0 = (swz / gx) * 128, col0 = (swz % gx) * 128;
  const int srow = lane >> 3, scol = (lane & 7) * 8;
  f32x4v acc[4][4];
#pragma unroll
  for (int i = 0; i < 4; ++i)
#pragma unroll
    for (int j = 0; j < 4; ++j) acc[i][j] = {0.f, 0.f, 0.f, 0.f};

  for (int k0 = 0; k0 < K; k0 += 64) {
    __syncthreads();
#pragma unroll
    for (int i = 0; i < 4; ++i) {
      const int rb = wid * 32 + i * 8;
      g2l16(&A[(size_t)(row0 + rb + srow) * K + k0 + scol], &As[rb * 64]);
      g2l16(&Bt[(size_t)(col0 + rb + srow) * K + k0 + scol], &Bs[rb * 64]);
    }
    __syncthreads();
#pragma unroll
    for (int kc = 0; kc < 2; ++kc) {
      s16x8 af[4], bfr[4];
#pragma unroll
      for (int mi = 0; mi < 4; ++mi)
        af[mi] = *(const s16x8*)&As[(wr * 64 + mi * 16 + lo4) * 64 + kc * 32 + hi2 * 8];
#pragma unroll
      for (int nj = 0; nj < 4; ++nj)
        bfr[nj] = *(const s16x8*)&Bs[(wc * 64 + nj * 16 + lo4) * 64 + kc * 32 + hi2 * 8];
#pragma unroll
      for (int mi = 0; mi < 4; ++mi)
#pragma unroll
        for (int nj = 0; nj < 4; ++nj)
          acc[mi][nj] = __builtin_amdgcn_mfma_f32_16x16x32_bf16(af[mi], bfr[nj], acc[mi][nj], 0, 0, 0);
    }
  }
#pragma unroll
  for (int mi = 0; mi < 4; ++mi)
#pragma unroll
    for (int nj = 0; nj < 4; ++nj)
#pragma unroll
      for (int r = 0; r < 4; ++r) {
        const int row = row0 + wr * 64 + mi * 16 + hi2 * 4 + r;
        const int col = col0 + wc * 64 + nj * 16 + lo4;
        C[(size_t)row * N + col] = f2bf(silu_(acc[mi][nj][r]));
      }
}

// ---------------- GEMM2: out = A2 @ WoT^T + b_out + hidden  M=4096 N=1024 K=3072, f32 out
__global__ __launch_bounds__(256) void hstu_gemm_out(const ushort_t* __restrict__ A,
                                                     const ushort_t* __restrict__ Bt,
                                                     const float* __restrict__ bout,
                                                     const float* __restrict__ hidden,
                                                     float* __restrict__ C) {
  constexpr int K = H3, N = Hh;
  __shared__ ushort_t As[128 * 64];
  __shared__ ushort_t Bs[64 * 64];
  const int tid = threadIdx.x, lane = tid & 63, wid = tid >> 6;
  const int lo4 = lane & 15, hi2 = lane >> 4;
  const int wr = wid >> 1, wc = wid & 1;
  // XCD swizzle: nwg = 16*32 = 512 (%8==0 -> bijective)
  const int gx = gridDim.x;
  const int lin = blockIdx.y * gx + blockIdx.x;
  const int cpx = (gx * gridDim.y) >> 3;
  const int swz = (lin & 7) * cpx + (lin >> 3);
  const int row0 = (swz / gx) * 128, col0 = (swz % gx) * 64;
  const int srow = lane >> 3, scol = (lane & 7) * 8;
  f32x4v acc[4][2];
#pragma unroll
  for (int i = 0; i < 4; ++i)
#pragma unroll
    for (int j = 0; j < 2; ++j) acc[i][j] = {0.f, 0.f, 0.f, 0.f};

  for (int k0 = 0; k0 < K; k0 += 64) {
    __syncthreads();
#pragma unroll
    for (int i = 0; i < 4; ++i) {
      const int rb = wid * 32 + i * 8;
      g2l16(&A[(size_t)(row0 + rb + srow) * K + k0 + scol], &As[rb * 64]);
    }
#pragma unroll
    for (int i = 0; i < 2; ++i) {
      const int rb = wid * 16 + i * 8;
      g2l16(&Bt[(size_t)(col0 + rb + srow) * K + k0 + scol], &Bs[rb * 64]);
    }
    __syncthreads();
#pragma unroll
    for (int kc = 0; kc < 2; ++kc) {
      s16x8 af[4], bfr[2];
#pragma unroll
      for (int mi = 0; mi < 4; ++mi)
        af[mi] = *(const s16x8*)&As[(wr * 64 + mi * 16 + lo4) * 64 + kc * 32 + hi2 * 8];
#pragma unroll
      for (int nj = 0; nj < 2; ++nj)
        bfr[nj] = *(const s16x8*)&Bs[(wc * 32 + nj * 16 + lo4) * 64 + kc * 32 + hi2 * 8];
#pragma unroll
      for (int mi = 0; mi < 4; ++mi)
#pragma unroll
        for (int nj = 0; nj < 2; ++nj)
          acc[mi][nj] = __builtin_amdgcn_mfma_f32_16x16x32_bf16(af[mi], bfr[nj], acc[mi][nj], 0, 0, 0);
    }
  }
#pragma unroll
  for (int mi = 0; mi < 4; ++mi)
#pragma unroll
    for (int nj = 0; nj < 2; ++nj)
#pragma unroll
      for (int r = 0; r < 4; ++r) {
        const int row = row0 + wr * 64 + mi * 16 + hi2 * 4 + r;
        const int col = col0 + wc * 32 + nj * 16 + lo4;
        C[(size_t)row * N + col] = acc[mi][nj][r] + bout[col] + hidden[(size_t)row * N + col];
      }
}

// ---------------- fused attention (R5-measured optimum, 152 µs). Block: (h, nblock, b),
// 8 waves, KVBLK=32. T14 split staging: issue loads(t+1) before compute(t), ds_write after
// PV barrier. Writes a2 = attn_out * gated. a2: [b][n][h*384 + {0:rope|128:ts|256:plain} + d]
__global__ __launch_bounds__(512, 4) void hstu_attn(const ushort_t* __restrict__ fused,
                                                    const ushort_t* __restrict__ qr,
                                                    const ushort_t* __restrict__ kr,
                                                    const ushort_t* __restrict__ vt,
                                                    const ushort_t* __restrict__ tsb,
                                                    const ushort_t* __restrict__ mtb,
                                                    ushort_t* __restrict__ a2) {
  __shared__ __align__(16) ushort_t Ks[32][136];
  __shared__ __align__(16) ushort_t KRs[32][136];
  __shared__ __align__(16) ushort_t Vt[128][40];   // Vt[dd][m]
  __shared__ __align__(16) ushort_t Pl[3][64][40]; // 0=plain 1=rope 2=ts
  __shared__ __align__(16) ushort_t Mt[64][40];    // mask as bf16 0/1

  const int tid = threadIdx.x;
  const int lane = tid & 63;
  const int wid = tid >> 6;  // 0..7
  const int lo4 = lane & 15;
  const int hi2 = lane >> 4;
  const int h = blockIdx.x;        // x = head -> linear%8 = h -> XCD pinning
  const int n0 = blockIdx.y * 64;
  const int b = blockIdx.z;
  const float inv_s = 1.0f / 2048.0f;

  // staging index constants
  const int krow = tid >> 4, kcol = (tid & 15) * 8;       // K/KR: 32 x 128
  const int vdd = tid >> 2, vmg = (tid & 3) * 8;          // Vt: 128 x 32
  const int trow = (tid & 255) >> 2, tmg = (tid & 3) * 8; // ts/mask: 64 x 32 (256 thr each)
  const ushort_t* TM = (wid < 4) ? tsb : mtb;             // waves 0-3: tsb, 4-7: mtb
  const size_t kbase = (size_t)b * Sq * H6 + 5 * Hh + h * HD + kcol;
  const size_t krbase = (size_t)b * Sq * Hh + h * HD + kcol;
  const size_t vbase = (size_t)((b * NH + h) * HD + vdd) * Sq + vmg;
  const size_t tbase = (size_t)(b * Sq + n0 + trow) * Sq + tmg;

  // ---- hoist Q fragments: wave = (type t_w, row-quarter rq)
  const int t_w = wid >> 2;  // 0=plain 1=rope
  const int rq = wid & 3;
  s16x8 qf[4];
  {
    const int row = tid >> 4;
    const int colg = (tid & 15) * 8;
#pragma unroll
    for (int half = 0; half < 2; ++half) {
      const size_t gr = (size_t)(b * Sq + n0 + half * 32 + row);
      *(s16x8*)&Ks[row][colg] = *(const s16x8*)&fused[gr * H6 + 4 * Hh + h * HD + colg];
      *(s16x8*)&KRs[row][colg] = *(const s16x8*)&qr[gr * Hh + h * HD + colg];
      __syncthreads();
      if ((rq >> 1) == half) {
        const int lrow = (rq & 1) * 16 + lo4;
        const ushort_t(*Qsrc)[136] = t_w ? KRs : Ks;
#pragma unroll
        for (int c = 0; c < 4; ++c)
          qf[c] = *(const s16x8*)&Qsrc[lrow][c * 32 + hi2 * 8];
      }
      __syncthreads();
    }
  }

  const f32x4v zero4 = {0.f, 0.f, 0.f, 0.f};
  f32x4v accO[3][2][2];
#pragma unroll
  for (int t = 0; t < 3; ++t)
#pragma unroll
    for (int rt = 0; rt < 2; ++rt)
#pragma unroll
      for (int ct = 0; ct < 2; ++ct) accO[t][rt][ct] = zero4;

  const int rh2 = wid >> 2;  // PV row-half
  const int cq = wid & 3;    // PV dd-quarter

  // prefetch registers
  s16x8 kreg, krreg, vreg, tmreg;
#define LOADT(T)                                                            \
  {                                                                         \
    const size_t moff = (size_t)(T) * 32;                                   \
    kreg = *(const s16x8*)&fused[kbase + (moff + krow) * H6];               \
    krreg = *(const s16x8*)&kr[krbase + (moff + krow) * Hh];                \
    vreg = *(const s16x8*)&vt[vbase + moff];                                \
    tmreg = *(const s16x8*)&TM[tbase + moff];                               \
  }
#define WRITET()                                                            \
  {                                                                         \
    *(s16x8*)&Ks[krow][kcol] = kreg;                                        \
    *(s16x8*)&KRs[krow][kcol] = krreg;                                      \
    *(s16x8*)&Vt[vdd][vmg] = vreg;                                          \
    if (wid < 4) *(s16x8*)&Pl[2][trow][tmg] = tmreg;                        \
    else *(s16x8*)&Mt[trow][tmg] = tmreg;                                   \
  }

  LOADT(0);
  WRITET();
  __syncthreads();

  for (int t = 0; t < Sq / 32; ++t) {
    if (t + 1 < Sq / 32) LOADT(t + 1);  // issue early (T14)
    // ---- scores: wave (t_w, rq) -> S[16 x 32] of its type
    {
      const ushort_t(*Kmat)[136] = t_w ? KRs : Ks;
#pragma unroll
      for (int mt2 = 0; mt2 < 2; ++mt2) {
        f32x4v a = zero4;
#pragma unroll
        for (int c = 0; c < 4; ++c) {
          s16x8 kf = *(const s16x8*)&Kmat[mt2 * 16 + lo4][c * 32 + hi2 * 8];
          a = __builtin_amdgcn_mfma_f32_16x16x32_bf16(qf[c], kf, a, 0, 0, 0);
        }
#pragma unroll
        for (int r = 0; r < 4; ++r) {
          const int n = rq * 16 + hi2 * 4 + r;
          const int m = mt2 * 16 + lo4;
          Pl[t_w][n][m] = f2bf(fmaxf(a[r], 0.f) * inv_s * bf2f(Mt[n][m]));
        }
      }
    }
    __syncthreads();
    // ---- PV: wave (rh2, cq): O[32 rows][32 dd] x 3 types
    {
      s16x8 af[3][2];
#pragma unroll
      for (int ty = 0; ty < 3; ++ty)
#pragma unroll
        for (int rt = 0; rt < 2; ++rt)
          af[ty][rt] = *(const s16x8*)&Pl[ty][rh2 * 32 + rt * 16 + lo4][hi2 * 8];
      s16x8 bfv[2];
#pragma unroll
      for (int ct = 0; ct < 2; ++ct)
        bfv[ct] = *(const s16x8*)&Vt[cq * 32 + ct * 16 + lo4][hi2 * 8];
#pragma unroll
      for (int ty = 0; ty < 3; ++ty)
#pragma unroll
        for (int rt = 0; rt < 2; ++rt)
#pragma unroll
          for (int ct = 0; ct < 2; ++ct)
            accO[ty][rt][ct] =
                __builtin_amdgcn_mfma_f32_16x16x32_bf16(af[ty][rt], bfv[ct], accO[ty][rt][ct], 0, 0, 0);
    }
    __syncthreads();
    // ---- write prefetched tile t+1 into LDS (write late, T14)
    if (t + 1 < Sq / 32) WRITET();
    __syncthreads();
  }
#undef LOADT
#undef WRITET

  // ---- epilogue: a2 = acc * gated (gated = fused[:, :3H], same 3H coordinate)
  const int toff[3] = {256, 0, 128};
#pragma unroll
  for (int ty = 0; ty < 3; ++ty)
#pragma unroll
    for (int rt = 0; rt < 2; ++rt)
#pragma unroll
      for (int ct = 0; ct < 2; ++ct)
#pragma unroll
        for (int r = 0; r < 4; ++r) {
          const int n = n0 + rh2 * 32 + rt * 16 + hi2 * 4 + r;
          const int dd = cq * 32 + ct * 16 + lo4;
          const int col3 = h * 384 + toff[ty] + dd;
          const float g = bf2f(fused[(size_t)(b * Sq + n) * H6 + col3]);
          a2[(size_t)(b * Sq + n) * H3 + col3] = f2bf(accO[ty][rt][ct][r] * g);
        }
}

// ---------------- RMS norm in-place (4096 rows x 1024), f32
__global__ __launch_bounds__(256) void hstu_rms(float* __restrict__ y,
                                                const float* __restrict__ w) {
  __shared__ float red[4];
  const int row = blockIdx.x;
  const int tid = threadIdx.x;
  float4 v = *(float4*)&y[(size_t)row * Hh + tid * 4];
  float ss = v.x * v.x + v.y * v.y + v.z * v.z + v.w * v.w;
#pragma unroll
  for (int o = 32; o > 0; o >>= 1) ss += __shfl_down(ss, o);
  if ((tid & 63) == 0) red[tid >> 6] = ss;
  __syncthreads();
  const float tot = red[0] + red[1] + red[2] + red[3];
  const float r = 1.0f / sqrtf(tot / (float)Hh + 1e-6f);
  float4 wv = *(const float4*)&w[tid * 4];
  v.x *= r * wv.x;
  v.y *= r * wv.y;
  v.z *= r * wv.z;
  v.w *= r * wv.w;
  *(float4*)&y[(size_t)row * Hh + tid * 4] = v;
}

extern "C" void kernel_launch(void* const* d_in, const int* in_sizes, int n_in,
                              void* d_out, int out_size, void* d_ws, size_t ws_size,
                              hipStream_t stream) {
  const float* hidden = (const float*)d_in[0];
  const void* mask = d_in[1];
  const float* bias = (const float*)d_in[2];
  const float* Wqkvu = (const float*)d_in[3];
  const float* Wout = (const float*)d_in[4];
  const float* bout = (const float*)d_in[5];
  const float* rmsw = (const float*)d_in[6];
  float* out = (float*)d_out;
  float* ws = (float*)d_ws;

  ushort_t* fused = (ushort_t*)(ws + FUSED_OFF);
  ushort_t* a2 = (ushort_t*)(ws + A2_OFF);
  ushort_t* hb = (ushort_t*)(ws + HB_OFF);
  ushort_t* mtbp = (ushort_t*)(ws + MTB_OFF);  // overlays hb/wqt (dead after gemm_silu)
  ushort_t* wqt = (ushort_t*)(ws + WQT_OFF);
  ushort_t* wot = (ushort_t*)(ws + WOT_OFF);
  ushort_t* qrb = (ushort_t*)(ws + QR_OFF);
  ushort_t* krb = (ushort_t*)(ws + KR_OFF);
  ushort_t* vtb = (ushort_t*)(ws + VT_OFF);
  float* tab = ws + TAB_OFF;
  int* mflag = (int*)(ws + FLAG_OFF);
  ushort_t* tsbp = (ushort_t*)(ws + TSB_OFF);

  hstu_mask_detect<<<1, 256, 0, stream>>>((const unsigned int*)mask, mflag);
  hstu_tab<<<512, 256, 0, stream>>>(tab);
  hstu_cvt<<<4096, 256, 0, stream>>>(hidden, hb, (Bz * Sq * Hh) / 4);
  hstu_cvt_t<<<dim3(H6 / 32, Hh / 32), 256, 0, stream>>>(Wqkvu, wqt, Hh, H6);
  hstu_cvt_t<<<dim3(Hh / 32, H3 / 32), 256, 0, stream>>>(Wout, wot, H3, Hh);
  hstu_gemm_silu<<<dim3(H6 / 128, (Bz * Sq) / 128), 256, 0, stream>>>(hb, wqt, fused);
  // msk AFTER gemm_silu: mtb overlays hb/wqt
  hstu_msk<<<(Bz * Sq * Sq / 8) / 256, 256, 0, stream>>>(
      (const int*)mask, (const unsigned char*)mask, mflag, bias, tsbp, mtbp);
  hstu_rope<<<(Bz * Sq * Hh / 8) / 256, 256, 0, stream>>>(fused, (const float2*)tab, qrb, krb);
  hstu_vt<<<dim3(Sq / 32, HD / 32, Bz * NH), 256, 0, stream>>>(fused, vtb);
  hstu_attn<<<dim3(NH, Sq / 64, Bz), 512, 0, stream>>>(fused, qrb, krb, vtb, tsbp, mtbp, a2);
  hstu_gemm_out<<<dim3(Hh / 64, (Bz * Sq) / 128), 256, 0, stream>>>(a2, wot, bout, hidden, out);
  hstu_rms<<<Bz * Sq, 256, 0, stream>>>(out, rmsw);
}

// Round 12
// 330.987 us; speedup vs baseline: 1.5353x; 1.1205x over previous
//
#include <hip/hip_runtime.h>
#include <math.h>

// Problem constants (B=2, S=2048, H=1024, NH=8, HD=128)
static constexpr int Bz = 2;
static constexpr int Sq = 2048;
static constexpr int Hh = 1024;
static constexpr int NH = 8;
static constexpr int HD = 128;
static constexpr int H3 = 3072;
static constexpr int H6 = 6144;

typedef unsigned short ushort_t;
typedef float f32x4v __attribute__((ext_vector_type(4)));
typedef short s16x8 __attribute__((ext_vector_type(8)));

// Workspace layout in float units (×4 bytes). Peak requirement ~146 MB.
static constexpr size_t FUSED_OFF = 0;          // bf16 [4096][6144] = 12,582,912 f
static constexpr size_t A2_OFF    = 12582912;   // bf16 [4096][3072] =  6,291,456 f
static constexpr size_t HB_OFF    = 18874368;   // bf16 [4096][1024] (dead after gemm_silu)
static constexpr size_t MTB_OFF   = 18874368;   // bf16 [2][2048][2048] (OVERLAYS hb+wqt)
static constexpr size_t WQT_OFF   = 20971520;   // bf16 [6144][1024] (dead after gemm_silu)
static constexpr size_t WOT_OFF   = 24117248;   // bf16 [1024][3072] =  1,572,864 f
static constexpr size_t QR_OFF    = 25690112;   // bf16 [4096][1024] =  2,097,152 f
static constexpr size_t KR_OFF    = 27787264;   // bf16 [4096][1024] =  2,097,152 f
static constexpr size_t VT_OFF    = 29884416;   // bf16 [16][128][2048] = 2,097,152 f
static constexpr size_t TAB_OFF   = 31981568;   // f32 S*64 float2 = 262,144 f
static constexpr size_t FLAG_OFF  = 32243712;   // 1 int (+pad)
static constexpr size_t TSB_OFF   = 32243716;   // bf16 [2][2048][2048] -> ends 36,438,020 f

__device__ __forceinline__ float silu_(float x) { return x / (1.0f + expf(-x)); }
__device__ __forceinline__ ushort_t f2bf(float x) {
  unsigned int u = __float_as_uint(x);
  u += 0x7fffu + ((u >> 16) & 1u);
  return (ushort_t)(u >> 16);
}
__device__ __forceinline__ float bf2f(ushort_t u) {
  return __uint_as_float(((unsigned int)u) << 16);
}
// async global->LDS 16B: per-lane global src, wave-uniform LDS base (+lane*16B by HW)
__device__ __forceinline__ void g2l16(const ushort_t* g, ushort_t* l) {
  __builtin_amdgcn_global_load_lds(
      (const __attribute__((address_space(1))) unsigned int*)g,
      (__attribute__((address_space(3))) unsigned int*)l, 16, 0, 0);
}

// ---------------- mask dtype detect: any 32-bit word > 1 => byte-packed bools.
// 32KB scan suffices (random 0/1 data: P[all 8192 words <=1 | u8-packed] ~ 2^-500).
__global__ __launch_bounds__(256) void hstu_mask_detect(const unsigned int* __restrict__ m,
                                                        int* __restrict__ flag) {
  __shared__ int s_any;
  if (threadIdx.x == 0) s_any = 0;
  __syncthreads();
  int any = 0;
  for (int i = threadIdx.x; i < 8192; i += 256)
    if (m[i] > 1u) any = 1;
  if (any) s_any = 1;
  __syncthreads();
  if (threadIdx.x == 0) *flag = s_any;
}

// ---------------- rope table: tab[s*64+i] = {cos,sin}(s * 10000^(-i/64))
__global__ __launch_bounds__(256) void hstu_tab(float* __restrict__ tab) {
  int t = blockIdx.x * 256 + threadIdx.x;
  int i = t & 63;
  int s = t >> 6;
  float inv = powf(10000.0f, -(float)i / 64.0f);
  float sn, cs;
  sincosf((float)s * inv, &sn, &cs);
  tab[2 * t + 0] = cs;
  tab[2 * t + 1] = sn;
}

// ---------------- mask/bias precompute: tsb = bf16(mask?bias:0), mtb = bf16(mask?inv_s:0)
__global__ __launch_bounds__(256) void hstu_msk(const int* __restrict__ mask32,
                                                const unsigned char* __restrict__ mask8,
                                                const int* __restrict__ mflag,
                                                const float* __restrict__ bias,
                                                ushort_t* __restrict__ tsb,
                                                ushort_t* __restrict__ mtb) {
  const size_t base = ((size_t)blockIdx.x * 256 + threadIdx.x) * 8;  // over B*S*S
  const int m_u8 = *mflag;
  const ushort_t ivs = f2bf(1.0f / 2048.0f);  // 2^-11, exact in bf16
  int mk[8];
  if (m_u8) {
    uchar4 a = *(const uchar4*)&mask8[base];
    uchar4 b = *(const uchar4*)&mask8[base + 4];
    mk[0] = a.x; mk[1] = a.y; mk[2] = a.z; mk[3] = a.w;
    mk[4] = b.x; mk[5] = b.y; mk[6] = b.z; mk[7] = b.w;
  } else {
    int4 a = *(const int4*)&mask32[base];
    int4 b = *(const int4*)&mask32[base + 4];
    mk[0] = a.x; mk[1] = a.y; mk[2] = a.z; mk[3] = a.w;
    mk[4] = b.x; mk[5] = b.y; mk[6] = b.z; mk[7] = b.w;
  }
  float4 b0 = *(const float4*)&bias[base];
  float4 b1 = *(const float4*)&bias[base + 4];
  float bb[8] = {b0.x, b0.y, b0.z, b0.w, b1.x, b1.y, b1.z, b1.w};
  ushort_t ts[8], mt[8];
#pragma unroll
  for (int i = 0; i < 8; ++i) {
    ts[i] = f2bf(mk[i] ? bb[i] : 0.0f);
    mt[i] = mk[i] ? ivs : (ushort_t)0u;
  }
  *(s16x8*)&tsb[base] = *(s16x8*)ts;
  *(s16x8*)&mtb[base] = *(s16x8*)mt;
}

// ---------------- f32 -> bf16 row-major copy (hidden)
__global__ __launch_bounds__(256) void hstu_cvt(const float* __restrict__ in,
                                                ushort_t* __restrict__ out, int n4) {
  int i = blockIdx.x * 256 + threadIdx.x;
  if (i >= n4) return;
  float4 v = *(const float4*)&in[(size_t)i * 4];
  ushort4 o;
  o.x = f2bf(v.x); o.y = f2bf(v.y); o.z = f2bf(v.z); o.w = f2bf(v.w);
  *(ushort4*)&out[(size_t)i * 4] = o;
}

// ---------------- f32 [K][N] -> bf16 [N][K] transpose-convert (weights)
__global__ __launch_bounds__(256) void hstu_cvt_t(const float* __restrict__ in,
                                                  ushort_t* __restrict__ out, int K, int N) {
  __shared__ float t[32][33];
  const int n0 = blockIdx.x * 32, k0 = blockIdx.y * 32;
  const int c = threadIdx.x & 31, rr = threadIdx.x >> 5;
#pragma unroll
  for (int p = 0; p < 4; ++p)
    t[rr + p * 8][c] = in[(size_t)(k0 + rr + p * 8) * N + n0 + c];
  __syncthreads();
#pragma unroll
  for (int p = 0; p < 4; ++p)
    out[(size_t)(n0 + rr + p * 8) * K + k0 + c] = f2bf(t[c][rr + p * 8]);
}

// ---------------- rope precompute: qr/kr[b][s][h*128+d] = rope(fused q/k), bf16
__global__ __launch_bounds__(256) void hstu_rope(const ushort_t* __restrict__ fused,
                                                 const float2* __restrict__ tab,
                                                 ushort_t* __restrict__ qr,
                                                 ushort_t* __restrict__ kr) {
  const int idx = blockIdx.x * 256 + threadIdx.x;  // over 4096*1024/8
  const int row = idx >> 7;
  const int cg = (idx & 127) * 8;
  const int s = row & (Sq - 1);
  const float2* trow = &tab[(size_t)s * 64 + ((cg & 127) >> 1)];
  float2 t[4];
#pragma unroll
  for (int p = 0; p < 4; ++p) t[p] = trow[p];

  s16x8 q8 = *(const s16x8*)&fused[(size_t)row * H6 + 4 * Hh + cg];
  s16x8 k8 = *(const s16x8*)&fused[(size_t)row * H6 + 5 * Hh + cg];
  ushort_t qo[8], ko[8];
#pragma unroll
  for (int p = 0; p < 4; ++p) {
    float qx = bf2f((ushort_t)q8[2 * p]), qy = bf2f((ushort_t)q8[2 * p + 1]);
    float kx = bf2f((ushort_t)k8[2 * p]), ky = bf2f((ushort_t)k8[2 * p + 1]);
    qo[2 * p] = f2bf(qx * t[p].x - qy * t[p].y);
    qo[2 * p + 1] = f2bf(qy * t[p].x + qx * t[p].y);
    ko[2 * p] = f2bf(kx * t[p].x - ky * t[p].y);
    ko[2 * p + 1] = f2bf(ky * t[p].x + kx * t[p].y);
  }
  *(s16x8*)&qr[(size_t)row * Hh + cg] = *(s16x8*)qo;
  *(s16x8*)&kr[(size_t)row * Hh + cg] = *(s16x8*)ko;
}

// ---------------- V transpose precompute: vt[(b*8+h)*128+dd][m] = V[b][m][h*128+dd]
__global__ __launch_bounds__(256) void hstu_vt(const ushort_t* __restrict__ fused,
                                               ushort_t* __restrict__ vt) {
  __shared__ ushort_t t[32][36];
  const int m0 = blockIdx.x * 32, d0 = blockIdx.y * 32, bh = blockIdx.z;
  const int b = bh >> 3, h = bh & 7;
  const int r = threadIdx.x >> 3, cg = (threadIdx.x & 7) * 4;
  *(ushort4*)&t[r][cg] =
      *(const ushort4*)&fused[(size_t)(b * Sq + m0 + r) * H6 + 3 * Hh + h * HD + d0 + cg];
  __syncthreads();
  ushort4 o;
  o.x = t[cg + 0][r]; o.y = t[cg + 1][r]; o.z = t[cg + 2][r]; o.w = t[cg + 3][r];
  *(ushort4*)&vt[(size_t)(bh * HD + d0 + r) * Sq + m0 + cg] = o;
}

// ---------------- GEMM1: fused = silu(hidden_bf @ WqT^T)  M=4096 N=6144 K=1024, bf16 out
__global__ __launch_bounds__(256) void hstu_gemm_silu(const ushort_t* __restrict__ A,
                                                      const ushort_t* __restrict__ Bt,
                                                      ushort_t* __restrict__ C) {
  constexpr int K = 1024, N = H6;
  __shared__ ushort_t As[128 * 64];
  __shared__ ushort_t Bs[128 * 64];
  const int tid = threadIdx.x, lane = tid & 63, wid = tid >> 6;
  const int lo4 = lane & 15, hi2 = lane >> 4;
  const int wr = wid >> 1, wc = wid & 1;
  const int row0 = blockIdx.y * 128, col0 = blockIdx.x * 128;
  const int srow = lane >> 3, scol = (lane & 7) * 8;
  f32x4v acc[4][4];
#pragma unroll
  for (int i = 0; i < 4; ++i)
#pragma unroll
    for (int j = 0; j < 4; ++j) acc[i][j] = {0.f, 0.f, 0.f, 0.f};

  for (int k0 = 0; k0 < K; k0 += 64) {
    __syncthreads();
#pragma unroll
    for (int i = 0; i < 4; ++i) {
      const int rb = wid * 32 + i * 8;
      g2l16(&A[(size_t)(row0 + rb + srow) * K + k0 + scol], &As[rb * 64]);
      g2l16(&Bt[(size_t)(col0 + rb + srow) * K + k0 + scol], &Bs[rb * 64]);
    }
    __syncthreads();
#pragma unroll
    for (int kc = 0; kc < 2; ++kc) {
      s16x8 af[4], bfr[4];
#pragma unroll
      for (int mi = 0; mi < 4; ++mi)
        af[mi] = *(const s16x8*)&As[(wr * 64 + mi * 16 + lo4) * 64 + kc * 32 + hi2 * 8];
#pragma unroll
      for (int nj = 0; nj < 4; ++nj)
        bfr[nj] = *(const s16x8*)&Bs[(wc * 64 + nj * 16 + lo4) * 64 + kc * 32 + hi2 * 8];
#pragma unroll
      for (int mi = 0; mi < 4; ++mi)
#pragma unroll
        for (int nj = 0; nj < 4; ++nj)
          acc[mi][nj] = __builtin_amdgcn_mfma_f32_16x16x32_bf16(af[mi], bfr[nj], acc[mi][nj], 0, 0, 0);
    }
  }
#pragma unroll
  for (int mi = 0; mi < 4; ++mi)
#pragma unroll
    for (int nj = 0; nj < 4; ++nj)
#pragma unroll
      for (int r = 0; r < 4; ++r) {
        const int row = row0 + wr * 64 + mi * 16 + hi2 * 4 + r;
        const int col = col0 + wc * 64 + nj * 16 + lo4;
        C[(size_t)row * N + col] = f2bf(silu_(acc[mi][nj][r]));
      }
}

// ---------------- GEMM2: out = A2 @ WoT^T + b_out + hidden  M=4096 N=1024 K=3072, f32 out
__global__ __launch_bounds__(256) void hstu_gemm_out(const ushort_t* __restrict__ A,
                                                     const ushort_t* __restrict__ Bt,
                                                     const float* __restrict__ bout,
                                                     const float* __restrict__ hidden,
                                                     float* __restrict__ C) {
  constexpr int K = H3, N = Hh;
  __shared__ ushort_t As[128 * 64];
  __shared__ ushort_t Bs[64 * 64];
  const int tid = threadIdx.x, lane = tid & 63, wid = tid >> 6;
  const int lo4 = lane & 15, hi2 = lane >> 4;
  const int wr = wid >> 1, wc = wid & 1;
  const int row0 = blockIdx.y * 128, col0 = blockIdx.x * 64;
  const int srow = lane >> 3, scol = (lane & 7) * 8;
  f32x4v acc[4][2];
#pragma unroll
  for (int i = 0; i < 4; ++i)
#pragma unroll
    for (int j = 0; j < 2; ++j) acc[i][j] = {0.f, 0.f, 0.f, 0.f};

  for (int k0 = 0; k0 < K; k0 += 64) {
    __syncthreads();
#pragma unroll
    for (int i = 0; i < 4; ++i) {
      const int rb = wid * 32 + i * 8;
      g2l16(&A[(size_t)(row0 + rb + srow) * K + k0 + scol], &As[rb * 64]);
    }
#pragma unroll
    for (int i = 0; i < 2; ++i) {
      const int rb = wid * 16 + i * 8;
      g2l16(&Bt[(size_t)(col0 + rb + srow) * K + k0 + scol], &Bs[rb * 64]);
    }
    __syncthreads();
#pragma unroll
    for (int kc = 0; kc < 2; ++kc) {
      s16x8 af[4], bfr[2];
#pragma unroll
      for (int mi = 0; mi < 4; ++mi)
        af[mi] = *(const s16x8*)&As[(wr * 64 + mi * 16 + lo4) * 64 + kc * 32 + hi2 * 8];
#pragma unroll
      for (int nj = 0; nj < 2; ++nj)
        bfr[nj] = *(const s16x8*)&Bs[(wc * 32 + nj * 16 + lo4) * 64 + kc * 32 + hi2 * 8];
#pragma unroll
      for (int mi = 0; mi < 4; ++mi)
#pragma unroll
        for (int nj = 0; nj < 2; ++nj)
          acc[mi][nj] = __builtin_amdgcn_mfma_f32_16x16x32_bf16(af[mi], bfr[nj], acc[mi][nj], 0, 0, 0);
    }
  }
#pragma unroll
  for (int mi = 0; mi < 4; ++mi)
#pragma unroll
    for (int nj = 0; nj < 2; ++nj)
#pragma unroll
      for (int r = 0; r < 4; ++r) {
        const int row = row0 + wr * 64 + mi * 16 + hi2 * 4 + r;
        const int col = col0 + wc * 32 + nj * 16 + lo4;
        C[(size_t)row * N + col] = acc[mi][nj][r] + bout[col] + hidden[(size_t)row * N + col];
      }
}

// ---------------- fused attention (R5 structure + swapped-score postproc). Block:
// (h, nblock, b), 8 waves, KVBLK=32. T14 split staging. Scores computed as S^T via
// mfma(kf, qf): lane holds fixed n=lo4, 4 consecutive m -> b64 Mt read + b64 Pl write.
// Mt holds mask*inv_s (folded). a2: [b][n][h*384 + {0:rope|128:ts|256:plain} + d]
__global__ __launch_bounds__(512, 4) void hstu_attn(const ushort_t* __restrict__ fused,
                                                    const ushort_t* __restrict__ qr,
                                                    const ushort_t* __restrict__ kr,
                                                    const ushort_t* __restrict__ vt,
                                                    const ushort_t* __restrict__ tsb,
                                                    const ushort_t* __restrict__ mtb,
                                                    ushort_t* __restrict__ a2) {
  __shared__ __align__(16) ushort_t Ks[32][136];
  __shared__ __align__(16) ushort_t KRs[32][136];
  __shared__ __align__(16) ushort_t Vt[128][40];   // Vt[dd][m]
  __shared__ __align__(16) ushort_t Pl[3][64][40]; // 0=plain 1=rope 2=ts
  __shared__ __align__(16) ushort_t Mt[64][40];    // mask*inv_s as bf16

  const int tid = threadIdx.x;
  const int lane = tid & 63;
  const int wid = tid >> 6;  // 0..7
  const int lo4 = lane & 15;
  const int hi2 = lane >> 4;
  const int h = blockIdx.x;        // x = head -> linear%8 = h -> XCD pinning
  const int n0 = blockIdx.y * 64;
  const int b = blockIdx.z;

  // staging index constants
  const int krow = tid >> 4, kcol = (tid & 15) * 8;       // K/KR: 32 x 128
  const int vdd = tid >> 2, vmg = (tid & 3) * 8;          // Vt: 128 x 32
  const int trow = (tid & 255) >> 2, tmg = (tid & 3) * 8; // ts/mask: 64 x 32 (256 thr each)
  const ushort_t* TM = (wid < 4) ? tsb : mtb;             // waves 0-3: tsb, 4-7: mtb
  const size_t kbase = (size_t)b * Sq * H6 + 5 * Hh + h * HD + kcol;
  const size_t krbase = (size_t)b * Sq * Hh + h * HD + kcol;
  const size_t vbase = (size_t)((b * NH + h) * HD + vdd) * Sq + vmg;
  const size_t tbase = (size_t)(b * Sq + n0 + trow) * Sq + tmg;

  // ---- hoist Q fragments: wave = (type t_w, row-quarter rq)
  const int t_w = wid >> 2;  // 0=plain 1=rope
  const int rq = wid & 3;
  s16x8 qf[4];
  {
    const int row = tid >> 4;
    const int colg = (tid & 15) * 8;
#pragma unroll
    for (int half = 0; half < 2; ++half) {
      const size_t gr = (size_t)(b * Sq + n0 + half * 32 + row);
      *(s16x8*)&Ks[row][colg] = *(const s16x8*)&fused[gr * H6 + 4 * Hh + h * HD + colg];
      *(s16x8*)&KRs[row][colg] = *(const s16x8*)&qr[gr * Hh + h * HD + colg];
      __syncthreads();
      if ((rq >> 1) == half) {
        const int lrow = (rq & 1) * 16 + lo4;
        const ushort_t(*Qsrc)[136] = t_w ? KRs : Ks;
#pragma unroll
        for (int c = 0; c < 4; ++c)
          qf[c] = *(const s16x8*)&Qsrc[lrow][c * 32 + hi2 * 8];
      }
      __syncthreads();
    }
  }

  const f32x4v zero4 = {0.f, 0.f, 0.f, 0.f};
  f32x4v accO[3][2][2];
#pragma unroll
  for (int t = 0; t < 3; ++t)
#pragma unroll
    for (int rt = 0; rt < 2; ++rt)
#pragma unroll
      for (int ct = 0; ct < 2; ++ct) accO[t][rt][ct] = zero4;

  const int rh2 = wid >> 2;  // PV row-half
  const int cq = wid & 3;    // PV dd-quarter

  // prefetch registers
  s16x8 kreg, krreg, vreg, tmreg;
#define LOADT(T)                                                            \
  {                                                                         \
    const size_t moff = (size_t)(T) * 32;                                   \
    kreg = *(const s16x8*)&fused[kbase + (moff + krow) * H6];               \
    krreg = *(const s16x8*)&kr[krbase + (moff + krow) * Hh];                \
    vreg = *(const s16x8*)&vt[vbase + moff];                                \
    tmreg = *(const s16x8*)&TM[tbase + moff];                               \
  }
#define WRITET()                                                            \
  {                                                                         \
    *(s16x8*)&Ks[krow][kcol] = kreg;                                        \
    *(s16x8*)&KRs[krow][kcol] = krreg;                                      \
    *(s16x8*)&Vt[vdd][vmg] = vreg;                                          \
    if (wid < 4) *(s16x8*)&Pl[2][trow][tmg] = tmreg;                        \
    else *(s16x8*)&Mt[trow][tmg] = tmreg;                                   \
  }

  LOADT(0);
  WRITET();
  __syncthreads();

  for (int t = 0; t < Sq / 32; ++t) {
    if (t + 1 < Sq / 32) LOADT(t + 1);  // issue early (T14)
    // ---- scores: wave (t_w, rq) -> S^T[32 m x 16 n]: lane owns n = rq*16+lo4,
    //      m = mt2*16 + hi2*4 + r (4 consecutive) -> b64 Mt read + b64 Pl write.
    {
      const ushort_t(*Kmat)[136] = t_w ? KRs : Ks;
      const int n = rq * 16 + lo4;
#pragma unroll
      for (int mt2 = 0; mt2 < 2; ++mt2) {
        f32x4v a = zero4;
#pragma unroll
        for (int c = 0; c < 4; ++c) {
          s16x8 kf = *(const s16x8*)&Kmat[mt2 * 16 + lo4][c * 32 + hi2 * 8];
          // SWAPPED: A = K-frag (rows=m), B = Q-frag (rows=n) => C[m][n]
          a = __builtin_amdgcn_mfma_f32_16x16x32_bf16(kf, qf[c], a, 0, 0, 0);
        }
        const int mb = mt2 * 16 + hi2 * 4;
        ushort4 mt4 = *(const ushort4*)&Mt[n][mb];  // Mt holds mask*inv_s
        ushort4 po;
        po.x = f2bf(fmaxf(a[0], 0.f) * bf2f(mt4.x));
        po.y = f2bf(fmaxf(a[1], 0.f) * bf2f(mt4.y));
        po.z = f2bf(fmaxf(a[2], 0.f) * bf2f(mt4.z));
        po.w = f2bf(fmaxf(a[3], 0.f) * bf2f(mt4.w));
        *(ushort4*)&Pl[t_w][n][mb] = po;
      }
    }
    __syncthreads();
    // ---- PV: wave (rh2, cq): O[32 rows][32 dd] x 3 types
    {
      s16x8 af[3][2];
#pragma unroll
      for (int ty = 0; ty < 3; ++ty)
#pragma unroll
        for (int rt = 0; rt < 2; ++rt)
          af[ty][rt] = *(const s16x8*)&Pl[ty][rh2 * 32 + rt * 16 + lo4][hi2 * 8];
      s16x8 bfv[2];
#pragma unroll
      for (int ct = 0; ct < 2; ++ct)
        bfv[ct] = *(const s16x8*)&Vt[cq * 32 + ct * 16 + lo4][hi2 * 8];
#pragma unroll
      for (int ty = 0; ty < 3; ++ty)
#pragma unroll
        for (int rt = 0; rt < 2; ++rt)
#pragma unroll
          for (int ct = 0; ct < 2; ++ct)
            accO[ty][rt][ct] =
                __builtin_amdgcn_mfma_f32_16x16x32_bf16(af[ty][rt], bfv[ct], accO[ty][rt][ct], 0, 0, 0);
    }
    __syncthreads();
    // ---- write prefetched tile t+1 into LDS (write late, T14)
    if (t + 1 < Sq / 32) WRITET();
    __syncthreads();
  }
#undef LOADT
#undef WRITET

  // ---- epilogue: a2 = acc * gated (gated = fused[:, :3H], same 3H coordinate)
  const int toff[3] = {256, 0, 128};
#pragma unroll
  for (int ty = 0; ty < 3; ++ty)
#pragma unroll
    for (int rt = 0; rt < 2; ++rt)
#pragma unroll
      for (int ct = 0; ct < 2; ++ct)
#pragma unroll
        for (int r = 0; r < 4; ++r) {
          const int n = n0 + rh2 * 32 + rt * 16 + hi2 * 4 + r;
          const int dd = cq * 32 + ct * 16 + lo4;
          const int col3 = h * 384 + toff[ty] + dd;
          const float g = bf2f(fused[(size_t)(b * Sq + n) * H6 + col3]);
          a2[(size_t)(b * Sq + n) * H3 + col3] = f2bf(accO[ty][rt][ct][r] * g);
        }
}

// ---------------- RMS norm in-place (4096 rows x 1024), f32
__global__ __launch_bounds__(256) void hstu_rms(float* __restrict__ y,
                                                const float* __restrict__ w) {
  __shared__ float red[4];
  const int row = blockIdx.x;
  const int tid = threadIdx.x;
  float4 v = *(float4*)&y[(size_t)row * Hh + tid * 4];
  float ss = v.x * v.x + v.y * v.y + v.z * v.z + v.w * v.w;
#pragma unroll
  for (int o = 32; o > 0; o >>= 1) ss += __shfl_down(ss, o);
  if ((tid & 63) == 0) red[tid >> 6] = ss;
  __syncthreads();
  const float tot = red[0] + red[1] + red[2] + red[3];
  const float r = 1.0f / sqrtf(tot / (float)Hh + 1e-6f);
  float4 wv = *(const float4*)&w[tid * 4];
  v.x *= r * wv.x;
  v.y *= r * wv.y;
  v.z *= r * wv.z;
  v.w *= r * wv.w;
  *(float4*)&y[(size_t)row * Hh + tid * 4] = v;
}

extern "C" void kernel_launch(void* const* d_in, const int* in_sizes, int n_in,
                              void* d_out, int out_size, void* d_ws, size_t ws_size,
                              hipStream_t stream) {
  const float* hidden = (const float*)d_in[0];
  const void* mask = d_in[1];
  const float* bias = (const float*)d_in[2];
  const float* Wqkvu = (const float*)d_in[3];
  const float* Wout = (const float*)d_in[4];
  const float* bout = (const float*)d_in[5];
  const float* rmsw = (const float*)d_in[6];
  float* out = (float*)d_out;
  float* ws = (float*)d_ws;

  ushort_t* fused = (ushort_t*)(ws + FUSED_OFF);
  ushort_t* a2 = (ushort_t*)(ws + A2_OFF);
  ushort_t* hb = (ushort_t*)(ws + HB_OFF);
  ushort_t* mtbp = (ushort_t*)(ws + MTB_OFF);  // overlays hb/wqt (dead after gemm_silu)
  ushort_t* wqt = (ushort_t*)(ws + WQT_OFF);
  ushort_t* wot = (ushort_t*)(ws + WOT_OFF);
  ushort_t* qrb = (ushort_t*)(ws + QR_OFF);
  ushort_t* krb = (ushort_t*)(ws + KR_OFF);
  ushort_t* vtb = (ushort_t*)(ws + VT_OFF);
  float* tab = ws + TAB_OFF;
  int* mflag = (int*)(ws + FLAG_OFF);
  ushort_t* tsbp = (ushort_t*)(ws + TSB_OFF);

  hstu_mask_detect<<<1, 256, 0, stream>>>((const unsigned int*)mask, mflag);
  hstu_tab<<<512, 256, 0, stream>>>(tab);
  hstu_cvt<<<4096, 256, 0, stream>>>(hidden, hb, (Bz * Sq * Hh) / 4);
  hstu_cvt_t<<<dim3(H6 / 32, Hh / 32), 256, 0, stream>>>(Wqkvu, wqt, Hh, H6);
  hstu_cvt_t<<<dim3(Hh / 32, H3 / 32), 256, 0, stream>>>(Wout, wot, H3, Hh);
  hstu_gemm_silu<<<dim3(H6 / 128, (Bz * Sq) / 128), 256, 0, stream>>>(hb, wqt, fused);
  // msk AFTER gemm_silu: mtb overlays hb/wqt
  hstu_msk<<<(Bz * Sq * Sq / 8) / 256, 256, 0, stream>>>(
      (const int*)mask, (const unsigned char*)mask, mflag, bias, tsbp, mtbp);
  hstu_rope<<<(Bz * Sq * Hh / 8) / 256, 256, 0, stream>>>(fused, (const float2*)tab, qrb, krb);
  hstu_vt<<<dim3(Sq / 32, HD / 32, Bz * NH), 256, 0, stream>>>(fused, vtb);
  hstu_attn<<<dim3(NH, Sq / 64, Bz), 512, 0, stream>>>(fused, qrb, krb, vtb, tsbp, mtbp, a2);
  hstu_gemm_out<<<dim3(Hh / 64, (Bz * Sq) / 128), 256, 0, stream>>>(a2, wot, bout, hidden, out);
  hstu_rms<<<Bz * Sq, 256, 0, stream>>>(out, rmsw);
}

// Round 13
// 327.569 us; speedup vs baseline: 1.5514x; 1.0104x over previous
//
#include <hip/hip_runtime.h>
#include <math.h>

// Problem constants (B=2, S=2048, H=1024, NH=8, HD=128)
static constexpr int Bz = 2;
static constexpr int Sq = 2048;
static constexpr int Hh = 1024;
static constexpr int NH = 8;
static constexpr int HD = 128;
static constexpr int H3 = 3072;
static constexpr int H6 = 6144;

typedef unsigned short ushort_t;
typedef float f32x4v __attribute__((ext_vector_type(4)));
typedef short s16x8 __attribute__((ext_vector_type(8)));

// Workspace layout in float units (×4 bytes). Peak requirement ~146 MB.
static constexpr size_t FUSED_OFF = 0;          // bf16 [4096][6144] = 12,582,912 f
static constexpr size_t A2_OFF    = 12582912;   // bf16 [4096][3072] =  6,291,456 f
static constexpr size_t HB_OFF    = 18874368;   // bf16 [4096][1024] (dead after gemm_silu)
static constexpr size_t MTB_OFF   = 18874368;   // bf16 [2][2048][2048] (OVERLAYS hb+wqt)
static constexpr size_t WQT_OFF   = 20971520;   // bf16 [6144][1024] (dead after gemm_silu)
static constexpr size_t WOT_OFF   = 24117248;   // bf16 [1024][3072] =  1,572,864 f
static constexpr size_t QR_OFF    = 25690112;   // bf16 [4096][1024] =  2,097,152 f
static constexpr size_t KR_OFF    = 27787264;   // bf16 [4096][1024] =  2,097,152 f
static constexpr size_t VT_OFF    = 29884416;   // bf16 [16][128][2048] = 2,097,152 f
static constexpr size_t TAB_OFF   = 31981568;   // f32 S*64 float2 = 262,144 f
static constexpr size_t FLAG_OFF  = 32243712;   // 1 int (+pad)
static constexpr size_t TSB_OFF   = 32243716;   // bf16 [2][2048][2048] -> ends 36,438,020 f

__device__ __forceinline__ float silu_(float x) { return x / (1.0f + expf(-x)); }
__device__ __forceinline__ ushort_t f2bf(float x) {
  unsigned int u = __float_as_uint(x);
  u += 0x7fffu + ((u >> 16) & 1u);
  return (ushort_t)(u >> 16);
}
__device__ __forceinline__ float bf2f(ushort_t u) {
  return __uint_as_float(((unsigned int)u) << 16);
}
// async global->LDS 16B: per-lane global src, wave-uniform LDS base (+lane*16B by HW)
__device__ __forceinline__ void g2l16(const ushort_t* g, ushort_t* l) {
  __builtin_amdgcn_global_load_lds(
      (const __attribute__((address_space(1))) unsigned int*)g,
      (__attribute__((address_space(3))) unsigned int*)l, 16, 0, 0);
}

// ---------------- fused: rope table (512 blocks) + mask dtype detect (block 512)
__global__ __launch_bounds__(256) void hstu_pre(const unsigned int* __restrict__ m,
                                                int* __restrict__ flag,
                                                float* __restrict__ tab) {
  __shared__ int s_any;
  if (blockIdx.x == 512) {  // detect: any 32-bit word > 1 => byte-packed bools
    if (threadIdx.x == 0) s_any = 0;
    __syncthreads();
    int any = 0;
    for (int i = threadIdx.x; i < 8192; i += 256)
      if (m[i] > 1u) any = 1;
    if (any) s_any = 1;
    __syncthreads();
    if (threadIdx.x == 0) *flag = s_any;
    return;
  }
  int t = blockIdx.x * 256 + threadIdx.x;  // < S*64
  int i = t & 63;
  int s = t >> 6;
  float inv = powf(10000.0f, -(float)i / 64.0f);
  float sn, cs;
  sincosf((float)s * inv, &sn, &cs);
  tab[2 * t + 0] = cs;
  tab[2 * t + 1] = sn;
}

// ---------------- mask/bias precompute: tsb = bf16(mask?bias:0), mtb = bf16(mask?inv_s:0)
__global__ __launch_bounds__(256) void hstu_msk(const int* __restrict__ mask32,
                                                const unsigned char* __restrict__ mask8,
                                                const int* __restrict__ mflag,
                                                const float* __restrict__ bias,
                                                ushort_t* __restrict__ tsb,
                                                ushort_t* __restrict__ mtb) {
  const size_t base = ((size_t)blockIdx.x * 256 + threadIdx.x) * 8;  // over B*S*S
  const int m_u8 = *mflag;
  const ushort_t ivs = f2bf(1.0f / 2048.0f);  // 2^-11, exact in bf16
  int mk[8];
  if (m_u8) {
    uchar4 a = *(const uchar4*)&mask8[base];
    uchar4 b = *(const uchar4*)&mask8[base + 4];
    mk[0] = a.x; mk[1] = a.y; mk[2] = a.z; mk[3] = a.w;
    mk[4] = b.x; mk[5] = b.y; mk[6] = b.z; mk[7] = b.w;
  } else {
    int4 a = *(const int4*)&mask32[base];
    int4 b = *(const int4*)&mask32[base + 4];
    mk[0] = a.x; mk[1] = a.y; mk[2] = a.z; mk[3] = a.w;
    mk[4] = b.x; mk[5] = b.y; mk[6] = b.z; mk[7] = b.w;
  }
  float4 b0 = *(const float4*)&bias[base];
  float4 b1 = *(const float4*)&bias[base + 4];
  float bb[8] = {b0.x, b0.y, b0.z, b0.w, b1.x, b1.y, b1.z, b1.w};
  ushort_t ts[8], mt[8];
#pragma unroll
  for (int i = 0; i < 8; ++i) {
    ts[i] = f2bf(mk[i] ? bb[i] : 0.0f);
    mt[i] = mk[i] ? ivs : (ushort_t)0u;
  }
  *(s16x8*)&tsb[base] = *(s16x8*)ts;
  *(s16x8*)&mtb[base] = *(s16x8*)mt;
}

// ---------------- fused conversions: hidden f32->bf16 (4096 blk) +
// Wqkvu [1024][6144] -> wqt [6144][1024] (6144 blk) + Wout [3072][1024] -> wot [1024][3072] (3072 blk)
__global__ __launch_bounds__(256) void hstu_cvt_all(const float* __restrict__ hidden,
                                                    ushort_t* __restrict__ hb,
                                                    const float* __restrict__ Wq,
                                                    ushort_t* __restrict__ wqt,
                                                    const float* __restrict__ Wo,
                                                    ushort_t* __restrict__ wot) {
  __shared__ float tbuf[32][33];
  const int blk = blockIdx.x;
  if (blk < 4096) {  // hidden copy-convert, exact fit 4096*256*4 = 4,194,304 floats
    const int idx = blk * 256 + threadIdx.x;
    float4 v = *(const float4*)&hidden[(size_t)idx * 4];
    ushort4 o;
    o.x = f2bf(v.x); o.y = f2bf(v.y); o.z = f2bf(v.z); o.w = f2bf(v.w);
    *(ushort4*)&hb[(size_t)idx * 4] = o;
    return;
  }
  const float* in;
  ushort_t* out;
  int K, N, n0, k0;
  if (blk < 4096 + 6144) {
    const int j = blk - 4096;
    in = Wq; out = wqt; K = 1024; N = 6144;
    n0 = (j % 192) * 32; k0 = (j / 192) * 32;
  } else {
    const int j = blk - 10240;
    in = Wo; out = wot; K = 3072; N = 1024;
    n0 = (j % 32) * 32; k0 = (j / 32) * 32;
  }
  const int c = threadIdx.x & 31, rr = threadIdx.x >> 5;
#pragma unroll
  for (int p = 0; p < 4; ++p)
    tbuf[rr + p * 8][c] = in[(size_t)(k0 + rr + p * 8) * N + n0 + c];
  __syncthreads();
#pragma unroll
  for (int p = 0; p < 4; ++p)
    out[(size_t)(n0 + rr + p * 8) * K + k0 + c] = f2bf(tbuf[c][rr + p * 8]);
}

// ---------------- fused: rope precompute (2048 blk) + V transpose (4096 blk)
__global__ __launch_bounds__(256) void hstu_prep2(const ushort_t* __restrict__ fused,
                                                  const float2* __restrict__ tab,
                                                  ushort_t* __restrict__ qr,
                                                  ushort_t* __restrict__ kr,
                                                  ushort_t* __restrict__ vt) {
  __shared__ ushort_t tbuf[32][36];
  const int blk = blockIdx.x;
  if (blk < 2048) {  // rope
    const int idx = blk * 256 + threadIdx.x;
    const int row = idx >> 7;
    const int cg = (idx & 127) * 8;
    const int s = row & (Sq - 1);
    const float2* trow = &tab[(size_t)s * 64 + ((cg & 127) >> 1)];
    float2 t[4];
#pragma unroll
    for (int p = 0; p < 4; ++p) t[p] = trow[p];
    s16x8 q8 = *(const s16x8*)&fused[(size_t)row * H6 + 4 * Hh + cg];
    s16x8 k8 = *(const s16x8*)&fused[(size_t)row * H6 + 5 * Hh + cg];
    ushort_t qo[8], ko[8];
#pragma unroll
    for (int p = 0; p < 4; ++p) {
      float qx = bf2f((ushort_t)q8[2 * p]), qy = bf2f((ushort_t)q8[2 * p + 1]);
      float kx = bf2f((ushort_t)k8[2 * p]), ky = bf2f((ushort_t)k8[2 * p + 1]);
      qo[2 * p] = f2bf(qx * t[p].x - qy * t[p].y);
      qo[2 * p + 1] = f2bf(qy * t[p].x + qx * t[p].y);
      ko[2 * p] = f2bf(kx * t[p].x - ky * t[p].y);
      ko[2 * p + 1] = f2bf(ky * t[p].x + kx * t[p].y);
    }
    *(s16x8*)&qr[(size_t)row * Hh + cg] = *(s16x8*)qo;
    *(s16x8*)&kr[(size_t)row * Hh + cg] = *(s16x8*)ko;
    return;
  }
  // vt: vt[(b*8+h)*128+dd][m] = V[b][m][h*128+dd]
  const int j = blk - 2048;
  const int m0 = (j & 63) * 32, d0 = ((j >> 6) & 3) * 32, bh = j >> 8;
  const int b = bh >> 3, h = bh & 7;
  const int r = threadIdx.x >> 3, cg = (threadIdx.x & 7) * 4;
  *(ushort4*)&tbuf[r][cg] =
      *(const ushort4*)&fused[(size_t)(b * Sq + m0 + r) * H6 + 3 * Hh + h * HD + d0 + cg];
  __syncthreads();
  ushort4 o;
  o.x = tbuf[cg + 0][r]; o.y = tbuf[cg + 1][r]; o.z = tbuf[cg + 2][r]; o.w = tbuf[cg + 3][r];
  *(ushort4*)&vt[(size_t)(bh * HD + d0 + r) * Sq + m0 + cg] = o;
}

// ---------------- GEMM1: fused = silu(hidden_bf @ WqT^T)  M=4096 N=6144 K=1024, bf16 out
__global__ __launch_bounds__(256) void hstu_gemm_silu(const ushort_t* __restrict__ A,
                                                      const ushort_t* __restrict__ Bt,
                                                      ushort_t* __restrict__ C) {
  constexpr int K = 1024, N = H6;
  __shared__ ushort_t As[128 * 64];
  __shared__ ushort_t Bs[128 * 64];
  const int tid = threadIdx.x, lane = tid & 63, wid = tid >> 6;
  const int lo4 = lane & 15, hi2 = lane >> 4;
  const int wr = wid >> 1, wc = wid & 1;
  const int row0 = blockIdx.y * 128, col0 = blockIdx.x * 128;
  const int srow = lane >> 3, scol = (lane & 7) * 8;
  f32x4v acc[4][4];
#pragma unroll
  for (int i = 0; i < 4; ++i)
#pragma unroll
    for (int j = 0; j < 4; ++j) acc[i][j] = {0.f, 0.f, 0.f, 0.f};

  for (int k0 = 0; k0 < K; k0 += 64) {
    __syncthreads();
#pragma unroll
    for (int i = 0; i < 4; ++i) {
      const int rb = wid * 32 + i * 8;
      g2l16(&A[(size_t)(row0 + rb + srow) * K + k0 + scol], &As[rb * 64]);
      g2l16(&Bt[(size_t)(col0 + rb + srow) * K + k0 + scol], &Bs[rb * 64]);
    }
    __syncthreads();
#pragma unroll
    for (int kc = 0; kc < 2; ++kc) {
      s16x8 af[4], bfr[4];
#pragma unroll
      for (int mi = 0; mi < 4; ++mi)
        af[mi] = *(const s16x8*)&As[(wr * 64 + mi * 16 + lo4) * 64 + kc * 32 + hi2 * 8];
#pragma unroll
      for (int nj = 0; nj < 4; ++nj)
        bfr[nj] = *(const s16x8*)&Bs[(wc * 64 + nj * 16 + lo4) * 64 + kc * 32 + hi2 * 8];
#pragma unroll
      for (int mi = 0; mi < 4; ++mi)
#pragma unroll
        for (int nj = 0; nj < 4; ++nj)
          acc[mi][nj] = __builtin_amdgcn_mfma_f32_16x16x32_bf16(af[mi], bfr[nj], acc[mi][nj], 0, 0, 0);
    }
  }
#pragma unroll
  for (int mi = 0; mi < 4; ++mi)
#pragma unroll
    for (int nj = 0; nj < 4; ++nj)
#pragma unroll
      for (int r = 0; r < 4; ++r) {
        const int row = row0 + wr * 64 + mi * 16 + hi2 * 4 + r;
        const int col = col0 + wc * 64 + nj * 16 + lo4;
        C[(size_t)row * N + col] = f2bf(silu_(acc[mi][nj][r]));
      }
}

// ---------------- GEMM2: out = A2 @ WoT^T + b_out + hidden  M=4096 N=1024 K=3072, f32 out
__global__ __launch_bounds__(256) void hstu_gemm_out(const ushort_t* __restrict__ A,
                                                     const ushort_t* __restrict__ Bt,
                                                     const float* __restrict__ bout,
                                                     const float* __restrict__ hidden,
                                                     float* __restrict__ C) {
  constexpr int K = H3, N = Hh;
  __shared__ ushort_t As[128 * 64];
  __shared__ ushort_t Bs[64 * 64];
  const int tid = threadIdx.x, lane = tid & 63, wid = tid >> 6;
  const int lo4 = lane & 15, hi2 = lane >> 4;
  const int wr = wid >> 1, wc = wid & 1;
  const int row0 = blockIdx.y * 128, col0 = blockIdx.x * 64;
  const int srow = lane >> 3, scol = (lane & 7) * 8;
  f32x4v acc[4][2];
#pragma unroll
  for (int i = 0; i < 4; ++i)
#pragma unroll
    for (int j = 0; j < 2; ++j) acc[i][j] = {0.f, 0.f, 0.f, 0.f};

  for (int k0 = 0; k0 < K; k0 += 64) {
    __syncthreads();
#pragma unroll
    for (int i = 0; i < 4; ++i) {
      const int rb = wid * 32 + i * 8;
      g2l16(&A[(size_t)(row0 + rb + srow) * K + k0 + scol], &As[rb * 64]);
    }
#pragma unroll
    for (int i = 0; i < 2; ++i) {
      const int rb = wid * 16 + i * 8;
      g2l16(&Bt[(size_t)(col0 + rb + srow) * K + k0 + scol], &Bs[rb * 64]);
    }
    __syncthreads();
#pragma unroll
    for (int kc = 0; kc < 2; ++kc) {
      s16x8 af[4], bfr[2];
#pragma unroll
      for (int mi = 0; mi < 4; ++mi)
        af[mi] = *(const s16x8*)&As[(wr * 64 + mi * 16 + lo4) * 64 + kc * 32 + hi2 * 8];
#pragma unroll
      for (int nj = 0; nj < 2; ++nj)
        bfr[nj] = *(const s16x8*)&Bs[(wc * 32 + nj * 16 + lo4) * 64 + kc * 32 + hi2 * 8];
#pragma unroll
      for (int mi = 0; mi < 4; ++mi)
#pragma unroll
        for (int nj = 0; nj < 2; ++nj)
          acc[mi][nj] = __builtin_amdgcn_mfma_f32_16x16x32_bf16(af[mi], bfr[nj], acc[mi][nj], 0, 0, 0);
    }
  }
#pragma unroll
  for (int mi = 0; mi < 4; ++mi)
#pragma unroll
    for (int nj = 0; nj < 2; ++nj)
#pragma unroll
      for (int r = 0; r < 4; ++r) {
        const int row = row0 + wr * 64 + mi * 16 + hi2 * 4 + r;
        const int col = col0 + wc * 32 + nj * 16 + lo4;
        C[(size_t)row * N + col] = acc[mi][nj][r] + bout[col] + hidden[(size_t)row * N + col];
      }
}

// ---------------- fused attention (R12 structure, now 2 barriers/iter via Vt/Pts dbuf).
// Block: (h, nblock, b), 8 waves, KVBLK=32, T14 split staging. Scores S^T via mfma(kf,qf).
// Phase A: LOADT(t+1) issue + scores(t). Phase B: PV(t) || WRITET(t+1) (Vt/Pts -> buf^1;
// Ks/KRs/Mt single-buffered: their last reader is phase A, one barrier before the write).
__global__ __launch_bounds__(512, 4) void hstu_attn(const ushort_t* __restrict__ fused,
                                                    const ushort_t* __restrict__ qr,
                                                    const ushort_t* __restrict__ kr,
                                                    const ushort_t* __restrict__ vt,
                                                    const ushort_t* __restrict__ tsb,
                                                    const ushort_t* __restrict__ mtb,
                                                    ushort_t* __restrict__ a2) {
  __shared__ __align__(16) ushort_t Ks[32][136];
  __shared__ __align__(16) ushort_t KRs[32][136];
  __shared__ __align__(16) ushort_t Vt[2][128][40];   // dbuf: Vt[buf][dd][m]
  __shared__ __align__(16) ushort_t Pl[2][64][40];    // 0=plain 1=rope (single: A->B handoff)
  __shared__ __align__(16) ushort_t Pts[2][64][40];   // ts scores, dbuf
  __shared__ __align__(16) ushort_t Mt[64][40];       // mask*inv_s as bf16

  const int tid = threadIdx.x;
  const int lane = tid & 63;
  const int wid = tid >> 6;  // 0..7
  const int lo4 = lane & 15;
  const int hi2 = lane >> 4;
  const int h = blockIdx.x;        // x = head -> linear%8 = h -> XCD pinning
  const int n0 = blockIdx.y * 64;
  const int b = blockIdx.z;
  constexpr int NT = Sq / 32;

  // staging index constants
  const int krow = tid >> 4, kcol = (tid & 15) * 8;       // K/KR: 32 x 128
  const int vdd = tid >> 2, vmg = (tid & 3) * 8;          // Vt: 128 x 32
  const int trow = (tid & 255) >> 2, tmg = (tid & 3) * 8; // ts/mask: 64 x 32 (256 thr each)
  const ushort_t* TM = (wid < 4) ? tsb : mtb;             // waves 0-3: tsb, 4-7: mtb
  const size_t kbase = (size_t)b * Sq * H6 + 5 * Hh + h * HD + kcol;
  const size_t krbase = (size_t)b * Sq * Hh + h * HD + kcol;
  const size_t vbase = (size_t)((b * NH + h) * HD + vdd) * Sq + vmg;
  const size_t tbase = (size_t)(b * Sq + n0 + trow) * Sq + tmg;

  // ---- hoist Q fragments: wave = (type t_w, row-quarter rq)
  const int t_w = wid >> 2;  // 0=plain 1=rope
  const int rq = wid & 3;
  s16x8 qf[4];
  {
    const int row = tid >> 4;
    const int colg = (tid & 15) * 8;
#pragma unroll
    for (int half = 0; half < 2; ++half) {
      const size_t gr = (size_t)(b * Sq + n0 + half * 32 + row);
      *(s16x8*)&Ks[row][colg] = *(const s16x8*)&fused[gr * H6 + 4 * Hh + h * HD + colg];
      *(s16x8*)&KRs[row][colg] = *(const s16x8*)&qr[gr * Hh + h * HD + colg];
      __syncthreads();
      if ((rq >> 1) == half) {
        const int lrow = (rq & 1) * 16 + lo4;
        const ushort_t(*Qsrc)[136] = t_w ? KRs : Ks;
#pragma unroll
        for (int c = 0; c < 4; ++c)
          qf[c] = *(const s16x8*)&Qsrc[lrow][c * 32 + hi2 * 8];
      }
      __syncthreads();
    }
  }

  const f32x4v zero4 = {0.f, 0.f, 0.f, 0.f};
  f32x4v accO[3][2][2];
#pragma unroll
  for (int t = 0; t < 3; ++t)
#pragma unroll
    for (int rt = 0; rt < 2; ++rt)
#pragma unroll
      for (int ct = 0; ct < 2; ++ct) accO[t][rt][ct] = zero4;

  const int rh2 = wid >> 2;  // PV row-half
  const int cq = wid & 3;    // PV dd-quarter

  // prefetch registers
  s16x8 kreg, krreg, vreg, tmreg;
#define LOADT(T)                                                            \
  {                                                                         \
    const size_t moff = (size_t)(T) * 32;                                   \
    kreg = *(const s16x8*)&fused[kbase + (moff + krow) * H6];               \
    krreg = *(const s16x8*)&kr[krbase + (moff + krow) * Hh];                \
    vreg = *(const s16x8*)&vt[vbase + moff];                                \
    tmreg = *(const s16x8*)&TM[tbase + moff];                               \
  }
#define WRITET(BUF)                                                         \
  {                                                                         \
    *(s16x8*)&Ks[krow][kcol] = kreg;                                        \
    *(s16x8*)&KRs[krow][kcol] = krreg;                                      \
    *(s16x8*)&Vt[BUF][vdd][vmg] = vreg;                                     \
    if (wid < 4) *(s16x8*)&Pts[BUF][trow][tmg] = tmreg;                     \
    else *(s16x8*)&Mt[trow][tmg] = tmreg;                                   \
  }

  LOADT(0);
  WRITET(0);
  __syncthreads();

  for (int t = 0; t < NT; ++t) {
    const int cur = t & 1;
    if (t + 1 < NT) LOADT(t + 1);  // issue early (T14), consumed in phase B
    // ---- phase A: scores(t): S^T via mfma(kf, qf); lane owns n=rq*16+lo4, 4 consecutive m
    {
      const ushort_t(*Kmat)[136] = t_w ? KRs : Ks;
      const int n = rq * 16 + lo4;
#pragma unroll
      for (int mt2 = 0; mt2 < 2; ++mt2) {
        f32x4v a = zero4;
#pragma unroll
        for (int c = 0; c < 4; ++c) {
          s16x8 kf = *(const s16x8*)&Kmat[mt2 * 16 + lo4][c * 32 + hi2 * 8];
          a = __builtin_amdgcn_mfma_f32_16x16x32_bf16(kf, qf[c], a, 0, 0, 0);
        }
        const int mb = mt2 * 16 + hi2 * 4;
        ushort4 mt4 = *(const ushort4*)&Mt[n][mb];  // Mt holds mask*inv_s
        ushort4 po;
        po.x = f2bf(fmaxf(a[0], 0.f) * bf2f(mt4.x));
        po.y = f2bf(fmaxf(a[1], 0.f) * bf2f(mt4.y));
        po.z = f2bf(fmaxf(a[2], 0.f) * bf2f(mt4.z));
        po.w = f2bf(fmaxf(a[3], 0.f) * bf2f(mt4.w));
        *(ushort4*)&Pl[t_w][n][mb] = po;
      }
    }
    __syncthreads();
    // ---- phase B: PV(t) reads Pl, Pts[cur], Vt[cur]; WRITET(t+1) -> Ks/KRs/Mt + buf cur^1
    {
      s16x8 af[3][2];
#pragma unroll
      for (int rt = 0; rt < 2; ++rt) {
        af[0][rt] = *(const s16x8*)&Pl[0][rh2 * 32 + rt * 16 + lo4][hi2 * 8];
        af[1][rt] = *(const s16x8*)&Pl[1][rh2 * 32 + rt * 16 + lo4][hi2 * 8];
        af[2][rt] = *(const s16x8*)&Pts[cur][rh2 * 32 + rt * 16 + lo4][hi2 * 8];
      }
      s16x8 bfv[2];
#pragma unroll
      for (int ct = 0; ct < 2; ++ct)
        bfv[ct] = *(const s16x8*)&Vt[cur][cq * 32 + ct * 16 + lo4][hi2 * 8];
      if (t + 1 < NT) WRITET(cur ^ 1);  // overlaps with MFMAs below
#pragma unroll
      for (int ty = 0; ty < 3; ++ty)
#pragma unroll
        for (int rt = 0; rt < 2; ++rt)
#pragma unroll
          for (int ct = 0; ct < 2; ++ct)
            accO[ty][rt][ct] =
                __builtin_amdgcn_mfma_f32_16x16x32_bf16(af[ty][rt], bfv[ct], accO[ty][rt][ct], 0, 0, 0);
    }
    __syncthreads();
  }
#undef LOADT
#undef WRITET

  // ---- epilogue: a2 = acc * gated (gated = fused[:, :3H], same 3H coordinate)
  const int toff[3] = {256, 0, 128};
#pragma unroll
  for (int ty = 0; ty < 3; ++ty)
#pragma unroll
    for (int rt = 0; rt < 2; ++rt)
#pragma unroll
      for (int ct = 0; ct < 2; ++ct)
#pragma unroll
        for (int r = 0; r < 4; ++r) {
          const int n = n0 + rh2 * 32 + rt * 16 + hi2 * 4 + r;
          const int dd = cq * 32 + ct * 16 + lo4;
          const int col3 = h * 384 + toff[ty] + dd;
          const float g = bf2f(fused[(size_t)(b * Sq + n) * H6 + col3]);
          a2[(size_t)(b * Sq + n) * H3 + col3] = f2bf(accO[ty][rt][ct][r] * g);
        }
}

// ---------------- RMS norm in-place (4096 rows x 1024), f32
__global__ __launch_bounds__(256) void hstu_rms(float* __restrict__ y,
                                                const float* __restrict__ w) {
  __shared__ float red[4];
  const int row = blockIdx.x;
  const int tid = threadIdx.x;
  float4 v = *(float4*)&y[(size_t)row * Hh + tid * 4];
  float ss = v.x * v.x + v.y * v.y + v.z * v.z + v.w * v.w;
#pragma unroll
  for (int o = 32; o > 0; o >>= 1) ss += __shfl_down(ss, o);
  if ((tid & 63) == 0) red[tid >> 6] = ss;
  __syncthreads();
  const float tot = red[0] + red[1] + red[2] + red[3];
  const float r = 1.0f / sqrtf(tot / (float)Hh + 1e-6f);
  float4 wv = *(const float4*)&w[tid * 4];
  v.x *= r * wv.x;
  v.y *= r * wv.y;
  v.z *= r * wv.z;
  v.w *= r * wv.w;
  *(float4*)&y[(size_t)row * Hh + tid * 4] = v;
}

extern "C" void kernel_launch(void* const* d_in, const int* in_sizes, int n_in,
                              void* d_out, int out_size, void* d_ws, size_t ws_size,
                              hipStream_t stream) {
  const float* hidden = (const float*)d_in[0];
  const void* mask = d_in[1];
  const float* bias = (const float*)d_in[2];
  const float* Wqkvu = (const float*)d_in[3];
  const float* Wout = (const float*)d_in[4];
  const float* bout = (const float*)d_in[5];
  const float* rmsw = (const float*)d_in[6];
  float* out = (float*)d_out;
  float* ws = (float*)d_ws;

  ushort_t* fused = (ushort_t*)(ws + FUSED_OFF);
  ushort_t* a2 = (ushort_t*)(ws + A2_OFF);
  ushort_t* hb = (ushort_t*)(ws + HB_OFF);
  ushort_t* mtbp = (ushort_t*)(ws + MTB_OFF);  // overlays hb/wqt (dead after gemm_silu)
  ushort_t* wqt = (ushort_t*)(ws + WQT_OFF);
  ushort_t* wot = (ushort_t*)(ws + WOT_OFF);
  ushort_t* qrb = (ushort_t*)(ws + QR_OFF);
  ushort_t* krb = (ushort_t*)(ws + KR_OFF);
  ushort_t* vtb = (ushort_t*)(ws + VT_OFF);
  float* tab = ws + TAB_OFF;
  int* mflag = (int*)(ws + FLAG_OFF);
  ushort_t* tsbp = (ushort_t*)(ws + TSB_OFF);

  hstu_pre<<<513, 256, 0, stream>>>((const unsigned int*)mask, mflag, tab);
  hstu_cvt_all<<<13312, 256, 0, stream>>>(hidden, hb, Wqkvu, wqt, Wout, wot);
  hstu_gemm_silu<<<dim3(H6 / 128, (Bz * Sq) / 128), 256, 0, stream>>>(hb, wqt, fused);
  // msk AFTER gemm_silu: mtb overlays hb/wqt
  hstu_msk<<<(Bz * Sq * Sq / 8) / 256, 256, 0, stream>>>(
      (const int*)mask, (const unsigned char*)mask, mflag, bias, tsbp, mtbp);
  hstu_prep2<<<6144, 256, 0, stream>>>(fused, (const float2*)tab, qrb, krb, vtb);
  hstu_attn<<<dim3(NH, Sq / 64, Bz), 512, 0, stream>>>(fused, qrb, krb, vtb, tsbp, mtbp, a2);
  hstu_gemm_out<<<dim3(Hh / 64, (Bz * Sq) / 128), 256, 0, stream>>>(a2, wot, bout, hidden, out);
  hstu_rms<<<Bz * Sq, 256, 0, stream>>>(out, rmsw);
}

// Round 14
// 310.801 us; speedup vs baseline: 1.6351x; 1.0540x over previous
//
#include <hip/hip_runtime.h>
#include <math.h>

// Problem constants (B=2, S=2048, H=1024, NH=8, HD=128)
static constexpr int Bz = 2;
static constexpr int Sq = 2048;
static constexpr int Hh = 1024;
static constexpr int NH = 8;
static constexpr int HD = 128;
static constexpr int H3 = 3072;
static constexpr int H6 = 6144;

typedef unsigned short ushort_t;
typedef float f32x4v __attribute__((ext_vector_type(4)));
typedef short s16x8 __attribute__((ext_vector_type(8)));

// Workspace layout in float units (×4 bytes). Peak 146.8 MB (< 152.04 known-good).
static constexpr size_t FUSED_OFF = 0;          // bf16 [4096][6144] = 12,582,912 f
static constexpr size_t A2_OFF    = 12582912;   // bf16 [4096][3072] =  6,291,456 f
static constexpr size_t HB_OFF    = 18874368;   // bf16 [4096][1024] (dead after gemm_silu)
static constexpr size_t WQT_OFF   = 20971520;   // bf16 [6144][1024] (dead after gemm_silu)
static constexpr size_t WOT_OFF   = 24117248;   // bf16 [1024][3072] =  1,572,864 f
static constexpr size_t QR_OFF    = 25690112;   // bf16 [4096][1024] =  2,097,152 f
static constexpr size_t KR_OFF    = 27787264;   // bf16 [4096][1024] =  2,097,152 f
static constexpr size_t VT_OFF    = 29884416;   // bf16 [16][128][2048] = 2,097,152 f
static constexpr size_t TAB_OFF   = 31981568;   // f32 S*64 float2 = 262,144 f
static constexpr size_t FLAG_OFF  = 32243712;   // 1 int (+pad)
static constexpr size_t TSB_OFF   = 32243716;   // bf16 [2][2048][2048] = 4,194,304 f
static constexpr size_t MBITS_OFF = 36438020;   // u32 [2][2048][64] = 262,144 f -> ends 36,700,164 f

__device__ __forceinline__ float silu_(float x) { return x / (1.0f + expf(-x)); }
__device__ __forceinline__ ushort_t f2bf(float x) {
  unsigned int u = __float_as_uint(x);
  u += 0x7fffu + ((u >> 16) & 1u);
  return (ushort_t)(u >> 16);
}
__device__ __forceinline__ float bf2f(ushort_t u) {
  return __uint_as_float(((unsigned int)u) << 16);
}
// async global->LDS 16B: per-lane global src, wave-uniform LDS base (+lane*16B by HW)
__device__ __forceinline__ void g2l16(const ushort_t* g, ushort_t* l) {
  __builtin_amdgcn_global_load_lds(
      (const __attribute__((address_space(1))) unsigned int*)g,
      (__attribute__((address_space(3))) unsigned int*)l, 16, 0, 0);
}

// ---------------- fused: rope table (512 blocks) + mask dtype detect (block 512)
__global__ __launch_bounds__(256) void hstu_pre(const unsigned int* __restrict__ m,
                                                int* __restrict__ flag,
                                                float* __restrict__ tab) {
  __shared__ int s_any;
  if (blockIdx.x == 512) {  // detect: any 32-bit word > 1 => byte-packed bools
    if (threadIdx.x == 0) s_any = 0;
    __syncthreads();
    int any = 0;
    for (int i = threadIdx.x; i < 8192; i += 256)
      if (m[i] > 1u) any = 1;
    if (any) s_any = 1;
    __syncthreads();
    if (threadIdx.x == 0) *flag = s_any;
    return;
  }
  int t = blockIdx.x * 256 + threadIdx.x;  // < S*64
  int i = t & 63;
  int s = t >> 6;
  float inv = powf(10000.0f, -(float)i / 64.0f);
  float sn, cs;
  sincosf((float)s * inv, &sn, &cs);
  tab[2 * t + 0] = cs;
  tab[2 * t + 1] = sn;
}

// ---------------- fused conversions: hidden f32->bf16 (4096 blk) +
// Wqkvu [1024][6144] -> wqt (6144 blk) + Wout [3072][1024] -> wot (3072 blk)
__global__ __launch_bounds__(256) void hstu_cvt_all(const float* __restrict__ hidden,
                                                    ushort_t* __restrict__ hb,
                                                    const float* __restrict__ Wq,
                                                    ushort_t* __restrict__ wqt,
                                                    const float* __restrict__ Wo,
                                                    ushort_t* __restrict__ wot) {
  __shared__ float tbuf[32][33];
  const int blk = blockIdx.x;
  if (blk < 4096) {  // hidden copy-convert
    const int idx = blk * 256 + threadIdx.x;
    float4 v = *(const float4*)&hidden[(size_t)idx * 4];
    ushort4 o;
    o.x = f2bf(v.x); o.y = f2bf(v.y); o.z = f2bf(v.z); o.w = f2bf(v.w);
    *(ushort4*)&hb[(size_t)idx * 4] = o;
    return;
  }
  const float* in;
  ushort_t* out;
  int K, N, n0, k0;
  if (blk < 4096 + 6144) {
    const int j = blk - 4096;
    in = Wq; out = wqt; K = 1024; N = 6144;
    n0 = (j % 192) * 32; k0 = (j / 192) * 32;
  } else {
    const int j = blk - 10240;
    in = Wo; out = wot; K = 3072; N = 1024;
    n0 = (j % 32) * 32; k0 = (j / 32) * 32;
  }
  const int c = threadIdx.x & 31, rr = threadIdx.x >> 5;
#pragma unroll
  for (int p = 0; p < 4; ++p)
    tbuf[rr + p * 8][c] = in[(size_t)(k0 + rr + p * 8) * N + n0 + c];
  __syncthreads();
#pragma unroll
  for (int p = 0; p < 4; ++p)
    out[(size_t)(n0 + rr + p * 8) * K + k0 + c] = f2bf(tbuf[c][rr + p * 8]);
}

// ---------------- MEGA: GEMM1 (blocks 0..1535) || msk (blocks 1536..5631).
// GEMM1: fused = silu(hidden_bf @ WqT^T)  M=4096 N=6144 K=1024, bf16 out (m97 structure).
// msk: tsb = bf16(mask?bias:0); mbits = bit-packed mask (u32 per 32 m). Pure BW — overlaps
// with the compute-bound GEMM blocks on the same CUs.
__global__ __launch_bounds__(256) void hstu_gemm_silu_msk(
    const ushort_t* __restrict__ A, const ushort_t* __restrict__ Bt,
    ushort_t* __restrict__ C, const int* __restrict__ mask32,
    const unsigned char* __restrict__ mask8, const int* __restrict__ mflag,
    const float* __restrict__ bias, ushort_t* __restrict__ tsb,
    unsigned char* __restrict__ mbits) {
  __shared__ ushort_t As[128 * 64];
  __shared__ ushort_t Bs[128 * 64];
  const int blk = blockIdx.x;
  const int tid = threadIdx.x;
  if (blk >= 1536) {  // ---- msk branch (no barriers, no LDS use)
    const size_t gt = (size_t)(blk - 1536) * 256 + tid;  // over B*S*S/8
    const size_t base = gt * 8;
    const int m_u8 = *mflag;
    int mk[8];
    if (m_u8) {
      uchar4 a = *(const uchar4*)&mask8[base];
      uchar4 b = *(const uchar4*)&mask8[base + 4];
      mk[0] = a.x; mk[1] = a.y; mk[2] = a.z; mk[3] = a.w;
      mk[4] = b.x; mk[5] = b.y; mk[6] = b.z; mk[7] = b.w;
    } else {
      int4 a = *(const int4*)&mask32[base];
      int4 b = *(const int4*)&mask32[base + 4];
      mk[0] = a.x; mk[1] = a.y; mk[2] = a.z; mk[3] = a.w;
      mk[4] = b.x; mk[5] = b.y; mk[6] = b.z; mk[7] = b.w;
    }
    float4 b0 = *(const float4*)&bias[base];
    float4 b1 = *(const float4*)&bias[base + 4];
    float bb[8] = {b0.x, b0.y, b0.z, b0.w, b1.x, b1.y, b1.z, b1.w};
    ushort_t ts[8];
    unsigned int byte = 0;
#pragma unroll
    for (int i = 0; i < 8; ++i) {
      ts[i] = f2bf(mk[i] ? bb[i] : 0.0f);
      byte |= (mk[i] ? 1u : 0u) << i;
    }
    *(s16x8*)&tsb[base] = *(s16x8*)ts;
    mbits[gt] = (unsigned char)byte;
    return;
  }
  // ---- GEMM branch
  constexpr int K = 1024, N = H6;
  const int lane = tid & 63, wid = tid >> 6;
  const int lo4 = lane & 15, hi2 = lane >> 4;
  const int wr = wid >> 1, wc = wid & 1;
  const int row0 = (blk / 48) * 128, col0 = (blk % 48) * 128;
  const int srow = lane >> 3, scol = (lane & 7) * 8;
  f32x4v acc[4][4];
#pragma unroll
  for (int i = 0; i < 4; ++i)
#pragma unroll
    for (int j = 0; j < 4; ++j) acc[i][j] = {0.f, 0.f, 0.f, 0.f};

  for (int k0 = 0; k0 < K; k0 += 64) {
    __syncthreads();
#pragma unroll
    for (int i = 0; i < 4; ++i) {
      const int rb = wid * 32 + i * 8;
      g2l16(&A[(size_t)(row0 + rb + srow) * K + k0 + scol], &As[rb * 64]);
      g2l16(&Bt[(size_t)(col0 + rb + srow) * K + k0 + scol], &Bs[rb * 64]);
    }
    __syncthreads();
#pragma unroll
    for (int kc = 0; kc < 2; ++kc) {
      s16x8 af[4], bfr[4];
#pragma unroll
      for (int mi = 0; mi < 4; ++mi)
        af[mi] = *(const s16x8*)&As[(wr * 64 + mi * 16 + lo4) * 64 + kc * 32 + hi2 * 8];
#pragma unroll
      for (int nj = 0; nj < 4; ++nj)
        bfr[nj] = *(const s16x8*)&Bs[(wc * 64 + nj * 16 + lo4) * 64 + kc * 32 + hi2 * 8];
#pragma unroll
      for (int mi = 0; mi < 4; ++mi)
#pragma unroll
        for (int nj = 0; nj < 4; ++nj)
          acc[mi][nj] = __builtin_amdgcn_mfma_f32_16x16x32_bf16(af[mi], bfr[nj], acc[mi][nj], 0, 0, 0);
    }
  }
#pragma unroll
  for (int mi = 0; mi < 4; ++mi)
#pragma unroll
    for (int nj = 0; nj < 4; ++nj)
#pragma unroll
      for (int r = 0; r < 4; ++r) {
        const int row = row0 + wr * 64 + mi * 16 + hi2 * 4 + r;
        const int col = col0 + wc * 64 + nj * 16 + lo4;
        C[(size_t)row * N + col] = f2bf(silu_(acc[mi][nj][r]));
      }
}

// ---------------- fused: rope precompute (2048 blk) + V transpose (4096 blk)
__global__ __launch_bounds__(256) void hstu_prep2(const ushort_t* __restrict__ fused,
                                                  const float2* __restrict__ tab,
                                                  ushort_t* __restrict__ qr,
                                                  ushort_t* __restrict__ kr,
                                                  ushort_t* __restrict__ vt) {
  __shared__ ushort_t tbuf[32][36];
  const int blk = blockIdx.x;
  if (blk < 2048) {  // rope
    const int idx = blk * 256 + threadIdx.x;
    const int row = idx >> 7;
    const int cg = (idx & 127) * 8;
    const int s = row & (Sq - 1);
    const float2* trow = &tab[(size_t)s * 64 + ((cg & 127) >> 1)];
    float2 t[4];
#pragma unroll
    for (int p = 0; p < 4; ++p) t[p] = trow[p];
    s16x8 q8 = *(const s16x8*)&fused[(size_t)row * H6 + 4 * Hh + cg];
    s16x8 k8 = *(const s16x8*)&fused[(size_t)row * H6 + 5 * Hh + cg];
    ushort_t qo[8], ko[8];
#pragma unroll
    for (int p = 0; p < 4; ++p) {
      float qx = bf2f((ushort_t)q8[2 * p]), qy = bf2f((ushort_t)q8[2 * p + 1]);
      float kx = bf2f((ushort_t)k8[2 * p]), ky = bf2f((ushort_t)k8[2 * p + 1]);
      qo[2 * p] = f2bf(qx * t[p].x - qy * t[p].y);
      qo[2 * p + 1] = f2bf(qy * t[p].x + qx * t[p].y);
      ko[2 * p] = f2bf(kx * t[p].x - ky * t[p].y);
      ko[2 * p + 1] = f2bf(ky * t[p].x + kx * t[p].y);
    }
    *(s16x8*)&qr[(size_t)row * Hh + cg] = *(s16x8*)qo;
    *(s16x8*)&kr[(size_t)row * Hh + cg] = *(s16x8*)ko;
    return;
  }
  // vt: vt[(b*8+h)*128+dd][m] = V[b][m][h*128+dd]
  const int j = blk - 2048;
  const int m0 = (j & 63) * 32, d0 = ((j >> 6) & 3) * 32, bh = j >> 8;
  const int b = bh >> 3, h = bh & 7;
  const int r = threadIdx.x >> 3, cg = (threadIdx.x & 7) * 4;
  *(ushort4*)&tbuf[r][cg] =
      *(const ushort4*)&fused[(size_t)(b * Sq + m0 + r) * H6 + 3 * Hh + h * HD + d0 + cg];
  __syncthreads();
  ushort4 o;
  o.x = tbuf[cg + 0][r]; o.y = tbuf[cg + 1][r]; o.z = tbuf[cg + 2][r]; o.w = tbuf[cg + 3][r];
  *(ushort4*)&vt[(size_t)(bh * HD + d0 + r) * Sq + m0 + cg] = o;
}

// ---------------- GEMM2: out = A2 @ WoT^T + b_out + hidden  M=4096 N=1024 K=3072, f32 out
__global__ __launch_bounds__(256) void hstu_gemm_out(const ushort_t* __restrict__ A,
                                                     const ushort_t* __restrict__ Bt,
                                                     const float* __restrict__ bout,
                                                     const float* __restrict__ hidden,
                                                     float* __restrict__ C) {
  constexpr int K = H3, N = Hh;
  __shared__ ushort_t As[128 * 64];
  __shared__ ushort_t Bs[64 * 64];
  const int tid = threadIdx.x, lane = tid & 63, wid = tid >> 6;
  const int lo4 = lane & 15, hi2 = lane >> 4;
  const int wr = wid >> 1, wc = wid & 1;
  const int row0 = blockIdx.y * 128, col0 = blockIdx.x * 64;
  const int srow = lane >> 3, scol = (lane & 7) * 8;
  f32x4v acc[4][2];
#pragma unroll
  for (int i = 0; i < 4; ++i)
#pragma unroll
    for (int j = 0; j < 2; ++j) acc[i][j] = {0.f, 0.f, 0.f, 0.f};

  for (int k0 = 0; k0 < K; k0 += 64) {
    __syncthreads();
#pragma unroll
    for (int i = 0; i < 4; ++i) {
      const int rb = wid * 32 + i * 8;
      g2l16(&A[(size_t)(row0 + rb + srow) * K + k0 + scol], &As[rb * 64]);
    }
#pragma unroll
    for (int i = 0; i < 2; ++i) {
      const int rb = wid * 16 + i * 8;
      g2l16(&Bt[(size_t)(col0 + rb + srow) * K + k0 + scol], &Bs[rb * 64]);
    }
    __syncthreads();
#pragma unroll
    for (int kc = 0; kc < 2; ++kc) {
      s16x8 af[4], bfr[2];
#pragma unroll
      for (int mi = 0; mi < 4; ++mi)
        af[mi] = *(const s16x8*)&As[(wr * 64 + mi * 16 + lo4) * 64 + kc * 32 + hi2 * 8];
#pragma unroll
      for (int nj = 0; nj < 2; ++nj)
        bfr[nj] = *(const s16x8*)&Bs[(wc * 32 + nj * 16 + lo4) * 64 + kc * 32 + hi2 * 8];
#pragma unroll
      for (int mi = 0; mi < 4; ++mi)
#pragma unroll
        for (int nj = 0; nj < 2; ++nj)
          acc[mi][nj] = __builtin_amdgcn_mfma_f32_16x16x32_bf16(af[mi], bfr[nj], acc[mi][nj], 0, 0, 0);
    }
  }
#pragma unroll
  for (int mi = 0; mi < 4; ++mi)
#pragma unroll
    for (int nj = 0; nj < 2; ++nj)
#pragma unroll
      for (int r = 0; r < 4; ++r) {
        const int row = row0 + wr * 64 + mi * 16 + hi2 * 4 + r;
        const int col = col0 + wc * 32 + nj * 16 + lo4;
        C[(size_t)row * N + col] = acc[mi][nj][r] + bout[col] + hidden[(size_t)row * N + col];
      }
}

// ---------------- fused attention (R11 3-barrier structure, Mt as u32 bit-plane).
// Block: (h, nblock, b), 8 waves, KVBLK=32. T14 split staging; scores S^T via mfma(kf,qf);
// lane owns n=rq*16+lo4, 4 consecutive m -> bit-test + b64 Pl write.
__global__ __launch_bounds__(512, 4) void hstu_attn(const ushort_t* __restrict__ fused,
                                                    const ushort_t* __restrict__ qr,
                                                    const ushort_t* __restrict__ kr,
                                                    const ushort_t* __restrict__ vt,
                                                    const ushort_t* __restrict__ tsb,
                                                    const unsigned int* __restrict__ mbits32,
                                                    ushort_t* __restrict__ a2) {
  __shared__ __align__(16) ushort_t Ks[32][136];
  __shared__ __align__(16) ushort_t KRs[32][136];
  __shared__ __align__(16) ushort_t Vt[128][40];   // Vt[dd][m]
  __shared__ __align__(16) ushort_t Pl[3][64][40]; // 0=plain 1=rope 2=ts
  __shared__ unsigned int Mt32[64];                // bit-packed mask row per n

  const int tid = threadIdx.x;
  const int lane = tid & 63;
  const int wid = tid >> 6;  // 0..7
  const int lo4 = lane & 15;
  const int hi2 = lane >> 4;
  const int h = blockIdx.x;        // x = head -> linear%8 = h -> XCD pinning
  const int n0 = blockIdx.y * 64;
  const int b = blockIdx.z;
  const float ivs = 1.0f / 2048.0f;
  constexpr int NT = Sq / 32;

  // staging index constants
  const int krow = tid >> 4, kcol = (tid & 15) * 8;       // K/KR: 32 x 128
  const int vdd = tid >> 2, vmg = (tid & 3) * 8;          // Vt: 128 x 32
  const int trow = (tid & 255) >> 2, tmg = (tid & 3) * 8; // ts: 64 x 32 (waves 0-3)
  const size_t kbase = (size_t)b * Sq * H6 + 5 * Hh + h * HD + kcol;
  const size_t krbase = (size_t)b * Sq * Hh + h * HD + kcol;
  const size_t vbase = (size_t)((b * NH + h) * HD + vdd) * Sq + vmg;
  const size_t tbase = (size_t)(b * Sq + n0 + trow) * Sq + tmg;
  const size_t mbase = (size_t)(b * Sq + n0 + lane) * 64;  // u32 stride 64/row

  // ---- hoist Q fragments: wave = (type t_w, row-quarter rq)
  const int t_w = wid >> 2;  // 0=plain 1=rope
  const int rq = wid & 3;
  s16x8 qf[4];
  {
    const int row = tid >> 4;
    const int colg = (tid & 15) * 8;
#pragma unroll
    for (int half = 0; half < 2; ++half) {
      const size_t gr = (size_t)(b * Sq + n0 + half * 32 + row);
      *(s16x8*)&Ks[row][colg] = *(const s16x8*)&fused[gr * H6 + 4 * Hh + h * HD + colg];
      *(s16x8*)&KRs[row][colg] = *(const s16x8*)&qr[gr * Hh + h * HD + colg];
      __syncthreads();
      if ((rq >> 1) == half) {
        const int lrow = (rq & 1) * 16 + lo4;
        const ushort_t(*Qsrc)[136] = t_w ? KRs : Ks;
#pragma unroll
        for (int c = 0; c < 4; ++c)
          qf[c] = *(const s16x8*)&Qsrc[lrow][c * 32 + hi2 * 8];
      }
      __syncthreads();
    }
  }

  const f32x4v zero4 = {0.f, 0.f, 0.f, 0.f};
  f32x4v accO[3][2][2];
#pragma unroll
  for (int t = 0; t < 3; ++t)
#pragma unroll
    for (int rt = 0; rt < 2; ++rt)
#pragma unroll
      for (int ct = 0; ct < 2; ++ct) accO[t][rt][ct] = zero4;

  const int rh2 = wid >> 2;  // PV row-half
  const int cq = wid & 3;    // PV dd-quarter

  // prefetch registers
  s16x8 kreg, krreg, vreg, tsreg;
  unsigned int mreg;
#define LOADT(T)                                                            \
  {                                                                         \
    const size_t moff = (size_t)(T) * 32;                                   \
    kreg = *(const s16x8*)&fused[kbase + (moff + krow) * H6];               \
    krreg = *(const s16x8*)&kr[krbase + (moff + krow) * Hh];                \
    vreg = *(const s16x8*)&vt[vbase + moff];                                \
    if (wid < 4) tsreg = *(const s16x8*)&tsb[tbase + moff];                 \
    else if (wid == 4) mreg = mbits32[mbase + (T)];                         \
  }
#define WRITET()                                                            \
  {                                                                         \
    *(s16x8*)&Ks[krow][kcol] = kreg;                                        \
    *(s16x8*)&KRs[krow][kcol] = krreg;                                      \
    *(s16x8*)&Vt[vdd][vmg] = vreg;                                          \
    if (wid < 4) *(s16x8*)&Pl[2][trow][tmg] = tsreg;                        \
    else if (wid == 4) Mt32[lane] = mreg;                                   \
  }

  LOADT(0);
  WRITET();
  __syncthreads();

  for (int t = 0; t < NT; ++t) {
    if (t + 1 < NT) LOADT(t + 1);  // issue early (T14)
    // ---- scores: S^T via mfma(kf, qf); mask via bit-test on Mt32[n]
    {
      const ushort_t(*Kmat)[136] = t_w ? KRs : Ks;
      const int n = rq * 16 + lo4;
      const unsigned int bits = Mt32[n];
#pragma unroll
      for (int mt2 = 0; mt2 < 2; ++mt2) {
        f32x4v a = zero4;
#pragma unroll
        for (int c = 0; c < 4; ++c) {
          s16x8 kf = *(const s16x8*)&Kmat[mt2 * 16 + lo4][c * 32 + hi2 * 8];
          a = __builtin_amdgcn_mfma_f32_16x16x32_bf16(kf, qf[c], a, 0, 0, 0);
        }
        const int mb = mt2 * 16 + hi2 * 4;
        ushort4 po;
        po.x = ((bits >> (mb + 0)) & 1u) ? f2bf(fmaxf(a[0], 0.f) * ivs) : (ushort_t)0;
        po.y = ((bits >> (mb + 1)) & 1u) ? f2bf(fmaxf(a[1], 0.f) * ivs) : (ushort_t)0;
        po.z = ((bits >> (mb + 2)) & 1u) ? f2bf(fmaxf(a[2], 0.f) * ivs) : (ushort_t)0;
        po.w = ((bits >> (mb + 3)) & 1u) ? f2bf(fmaxf(a[3], 0.f) * ivs) : (ushort_t)0;
        *(ushort4*)&Pl[t_w][n][mb] = po;
      }
    }
    __syncthreads();
    // ---- PV: wave (rh2, cq): O[32 rows][32 dd] x 3 types
    {
      s16x8 af[3][2];
#pragma unroll
      for (int ty = 0; ty < 3; ++ty)
#pragma unroll
        for (int rt = 0; rt < 2; ++rt)
          af[ty][rt] = *(const s16x8*)&Pl[ty][rh2 * 32 + rt * 16 + lo4][hi2 * 8];
      s16x8 bfv[2];
#pragma unroll
      for (int ct = 0; ct < 2; ++ct)
        bfv[ct] = *(const s16x8*)&Vt[cq * 32 + ct * 16 + lo4][hi2 * 8];
#pragma unroll
      for (int ty = 0; ty < 3; ++ty)
#pragma unroll
        for (int rt = 0; rt < 2; ++rt)
#pragma unroll
          for (int ct = 0; ct < 2; ++ct)
            accO[ty][rt][ct] =
                __builtin_amdgcn_mfma_f32_16x16x32_bf16(af[ty][rt], bfv[ct], accO[ty][rt][ct], 0, 0, 0);
    }
    __syncthreads();
    // ---- write prefetched tile t+1 into LDS (write late, T14)
    if (t + 1 < NT) WRITET();
    __syncthreads();
  }
#undef LOADT
#undef WRITET

  // ---- epilogue: a2 = acc * gated (gated = fused[:, :3H], same 3H coordinate)
  const int toff[3] = {256, 0, 128};
#pragma unroll
  for (int ty = 0; ty < 3; ++ty)
#pragma unroll
    for (int rt = 0; rt < 2; ++rt)
#pragma unroll
      for (int ct = 0; ct < 2; ++ct)
#pragma unroll
        for (int r = 0; r < 4; ++r) {
          const int n = n0 + rh2 * 32 + rt * 16 + hi2 * 4 + r;
          const int dd = cq * 32 + ct * 16 + lo4;
          const int col3 = h * 384 + toff[ty] + dd;
          const float g = bf2f(fused[(size_t)(b * Sq + n) * H6 + col3]);
          a2[(size_t)(b * Sq + n) * H3 + col3] = f2bf(accO[ty][rt][ct][r] * g);
        }
}

// ---------------- RMS norm in-place (4096 rows x 1024), f32
__global__ __launch_bounds__(256) void hstu_rms(float* __restrict__ y,
                                                const float* __restrict__ w) {
  __shared__ float red[4];
  const int row = blockIdx.x;
  const int tid = threadIdx.x;
  float4 v = *(float4*)&y[(size_t)row * Hh + tid * 4];
  float ss = v.x * v.x + v.y * v.y + v.z * v.z + v.w * v.w;
#pragma unroll
  for (int o = 32; o > 0; o >>= 1) ss += __shfl_down(ss, o);
  if ((tid & 63) == 0) red[tid >> 6] = ss;
  __syncthreads();
  const float tot = red[0] + red[1] + red[2] + red[3];
  const float r = 1.0f / sqrtf(tot / (float)Hh + 1e-6f);
  float4 wv = *(const float4*)&w[tid * 4];
  v.x *= r * wv.x;
  v.y *= r * wv.y;
  v.z *= r * wv.z;
  v.w *= r * wv.w;
  *(float4*)&y[(size_t)row * Hh + tid * 4] = v;
}

extern "C" void kernel_launch(void* const* d_in, const int* in_sizes, int n_in,
                              void* d_out, int out_size, void* d_ws, size_t ws_size,
                              hipStream_t stream) {
  const float* hidden = (const float*)d_in[0];
  const void* mask = d_in[1];
  const float* bias = (const float*)d_in[2];
  const float* Wqkvu = (const float*)d_in[3];
  const float* Wout = (const float*)d_in[4];
  const float* bout = (const float*)d_in[5];
  const float* rmsw = (const float*)d_in[6];
  float* out = (float*)d_out;
  float* ws = (float*)d_ws;

  ushort_t* fused = (ushort_t*)(ws + FUSED_OFF);
  ushort_t* a2 = (ushort_t*)(ws + A2_OFF);
  ushort_t* hb = (ushort_t*)(ws + HB_OFF);
  ushort_t* wqt = (ushort_t*)(ws + WQT_OFF);
  ushort_t* wot = (ushort_t*)(ws + WOT_OFF);
  ushort_t* qrb = (ushort_t*)(ws + QR_OFF);
  ushort_t* krb = (ushort_t*)(ws + KR_OFF);
  ushort_t* vtb = (ushort_t*)(ws + VT_OFF);
  float* tab = ws + TAB_OFF;
  int* mflag = (int*)(ws + FLAG_OFF);
  ushort_t* tsbp = (ushort_t*)(ws + TSB_OFF);
  unsigned char* mbits = (unsigned char*)(ws + MBITS_OFF);

  hstu_pre<<<513, 256, 0, stream>>>((const unsigned int*)mask, mflag, tab);
  hstu_cvt_all<<<13312, 256, 0, stream>>>(hidden, hb, Wqkvu, wqt, Wout, wot);
  hstu_gemm_silu_msk<<<1536 + 4096, 256, 0, stream>>>(
      hb, wqt, fused, (const int*)mask, (const unsigned char*)mask, mflag, bias, tsbp, mbits);
  hstu_prep2<<<6144, 256, 0, stream>>>(fused, (const float2*)tab, qrb, krb, vtb);
  hstu_attn<<<dim3(NH, Sq / 64, Bz), 512, 0, stream>>>(
      fused, qrb, krb, vtb, tsbp, (const unsigned int*)mbits, a2);
  hstu_gemm_out<<<dim3(Hh / 64, (Bz * Sq) / 128), 256, 0, stream>>>(a2, wot, bout, hidden, out);
  hstu_rms<<<Bz * Sq, 256, 0, stream>>>(out, rmsw);
}